// Round 1
// baseline (1012.258 us; speedup 1.0000x reference)
//
#include <hip/hip_runtime.h>
#include <math.h>

// MHSA fp32 baseline.
// ws layout: Q at 0, K at +16MB, V at +32MB, each [N*H][WH][32] head-major fp32.
#define WH 2048
#define DM 256
#define NHD 8
#define DH 32
#define NB 8

// ---------------- QKV projection GEMM ----------------
// C(16384x256) = X(16384x256) @ W(256x256) + b ; z in {0,1,2} selects Q/K/V.
// BM=BN=128, BK=16, 256 threads, 8x8 micro-tile.
__global__ __launch_bounds__(256) void qkv_gemm(
    const float* __restrict__ X,
    const float* __restrict__ Wq, const float* __restrict__ bq,
    const float* __restrict__ Wk, const float* __restrict__ bk,
    const float* __restrict__ Wv, const float* __restrict__ bv,
    float* __restrict__ Qb, float* __restrict__ Kb, float* __restrict__ Vb)
{
    const float* W; const float* bias; float* Ob;
    if (blockIdx.z == 0)      { W = Wq; bias = bq; Ob = Qb; }
    else if (blockIdx.z == 1) { W = Wk; bias = bk; Ob = Kb; }
    else                      { W = Wv; bias = bv; Ob = Vb; }

    __shared__ float Xt[16][132];   // transposed X tile: Xt[k][row], pad to 132 (16B-aligned rows)
    __shared__ float Ws[16][132];   // W tile: Ws[k][col]

    const int tid = threadIdx.x;
    const int bm = blockIdx.x * 128;
    const int bn = blockIdx.y * 128;
    const int ty = tid >> 4;        // 0..15 -> row group
    const int tx = tid & 15;        // 0..15 -> col group

    float acc[8][8];
    #pragma unroll
    for (int i = 0; i < 8; i++)
        #pragma unroll
        for (int j = 0; j < 8; j++) acc[i][j] = 0.f;

    for (int k0 = 0; k0 < DM; k0 += 16) {
        // X tile load (rows bm..bm+127, k k0..k0+15), transpose into LDS
        #pragma unroll
        for (int it = 0; it < 2; it++) {
            int r  = (tid >> 2) + it * 64;
            int kc = (tid & 3) * 4;
            float4 v = *(const float4*)&X[(size_t)(bm + r) * DM + k0 + kc];
            Xt[kc + 0][r] = v.x; Xt[kc + 1][r] = v.y;
            Xt[kc + 2][r] = v.z; Xt[kc + 3][r] = v.w;
        }
        // W tile load (k k0..k0+15, cols bn..bn+127)
        #pragma unroll
        for (int it = 0; it < 2; it++) {
            int kr = (tid >> 5) + it * 8;
            int c4 = (tid & 31) * 4;
            *(float4*)&Ws[kr][c4] = *(const float4*)&W[(size_t)(k0 + kr) * DM + bn + c4];
        }
        __syncthreads();
        #pragma unroll
        for (int kk = 0; kk < 16; kk++) {
            float4 a0 = *(const float4*)&Xt[kk][ty * 8];
            float4 a1 = *(const float4*)&Xt[kk][ty * 8 + 4];
            float4 b0 = *(const float4*)&Ws[kk][tx * 8];
            float4 b1 = *(const float4*)&Ws[kk][tx * 8 + 4];
            float a[8] = {a0.x, a0.y, a0.z, a0.w, a1.x, a1.y, a1.z, a1.w};
            float b[8] = {b0.x, b0.y, b0.z, b0.w, b1.x, b1.y, b1.z, b1.w};
            #pragma unroll
            for (int i = 0; i < 8; i++)
                #pragma unroll
                for (int j = 0; j < 8; j++)
                    acc[i][j] = fmaf(a[i], b[j], acc[i][j]);
        }
        __syncthreads();
    }

    // epilogue: bias + store head-major [n*H+h][w][d]
    float bv8[8];
    #pragma unroll
    for (int j = 0; j < 8; j++) bv8[j] = bias[bn + tx * 8 + j];

    #pragma unroll
    for (int i = 0; i < 8; i++) {
        int r = bm + ty * 8 + i;
        int n = r >> 11;            // /WH
        int w = r & (WH - 1);
        #pragma unroll
        for (int j4 = 0; j4 < 2; j4++) {
            int c = bn + tx * 8 + j4 * 4;
            int h = c >> 5, d = c & 31;
            float4 o;
            o.x = acc[i][j4 * 4 + 0] + bv8[j4 * 4 + 0];
            o.y = acc[i][j4 * 4 + 1] + bv8[j4 * 4 + 1];
            o.z = acc[i][j4 * 4 + 2] + bv8[j4 * 4 + 2];
            o.w = acc[i][j4 * 4 + 3] + bv8[j4 * 4 + 3];
            *(float4*)&Ob[(((size_t)n * NHD + h) * WH + w) * DH + d] = o;
        }
    }
}

// ---------------- flash attention (fp32, online softmax) ----------------
// block = 128 threads, each thread owns 2 query rows (r0 = q0+tid, r1 = r0+128).
// 64-key LDS tiles, 16-key register sub-chunks. logits scaled by sqrt(32).
__global__ __launch_bounds__(128) void attn(
    const float* __restrict__ Qb, const float* __restrict__ Kb,
    const float* __restrict__ Vb, const float* __restrict__ X,
    float* __restrict__ Out)
{
    __shared__ float Ks[64 * 32];
    __shared__ float Vs[64 * 32];

    const int tid = threadIdx.x;
    const int nh = blockIdx.y;
    const int q0 = blockIdx.x * 256;
    const size_t base = (size_t)nh * WH * DH;
    const int r0 = q0 + tid, r1 = q0 + tid + 128;

    float q0r[32], q1r[32];
    #pragma unroll
    for (int d4 = 0; d4 < 8; d4++) {
        float4 a = *(const float4*)&Qb[base + (size_t)r0 * DH + d4 * 4];
        q0r[d4*4+0] = a.x; q0r[d4*4+1] = a.y; q0r[d4*4+2] = a.z; q0r[d4*4+3] = a.w;
        float4 b = *(const float4*)&Qb[base + (size_t)r1 * DH + d4 * 4];
        q1r[d4*4+0] = b.x; q1r[d4*4+1] = b.y; q1r[d4*4+2] = b.z; q1r[d4*4+3] = b.w;
    }

    float o0[32], o1[32];
    #pragma unroll
    for (int d = 0; d < 32; d++) { o0[d] = 0.f; o1[d] = 0.f; }
    float m0 = -INFINITY, m1 = -INFINITY, l0 = 0.f, l1 = 0.f;
    const float scale = 5.65685424949238f;   // sqrt(32), faithful to source

    for (int kt = 0; kt < WH / 64; kt++) {
        // stage K/V tile (64 keys x 32 dims)
        #pragma unroll
        for (int i = 0; i < 4; i++) {
            int f = tid + 128 * i;
            *(float4*)&Ks[f * 4] = *(const float4*)&Kb[base + (size_t)kt * 2048 + f * 4];
            *(float4*)&Vs[f * 4] = *(const float4*)&Vb[base + (size_t)kt * 2048 + f * 4];
        }
        __syncthreads();

        for (int sc = 0; sc < 4; sc++) {
            float s0[16], s1[16];
            #pragma unroll
            for (int j = 0; j < 16; j++) {
                const float* kp = &Ks[(sc * 16 + j) * 32];
                float a0 = 0.f, a1 = 0.f;
                #pragma unroll
                for (int d4 = 0; d4 < 8; d4++) {
                    float4 kv = *(const float4*)(kp + d4 * 4);
                    a0 = fmaf(q0r[d4*4+0], kv.x, a0);
                    a0 = fmaf(q0r[d4*4+1], kv.y, a0);
                    a0 = fmaf(q0r[d4*4+2], kv.z, a0);
                    a0 = fmaf(q0r[d4*4+3], kv.w, a0);
                    a1 = fmaf(q1r[d4*4+0], kv.x, a1);
                    a1 = fmaf(q1r[d4*4+1], kv.y, a1);
                    a1 = fmaf(q1r[d4*4+2], kv.z, a1);
                    a1 = fmaf(q1r[d4*4+3], kv.w, a1);
                }
                s0[j] = a0 * scale;
                s1[j] = a1 * scale;
            }
            float cm0 = s0[0], cm1 = s1[0];
            #pragma unroll
            for (int j = 1; j < 16; j++) { cm0 = fmaxf(cm0, s0[j]); cm1 = fmaxf(cm1, s1[j]); }
            float mn0 = fmaxf(m0, cm0), mn1 = fmaxf(m1, cm1);
            float al0 = __expf(m0 - mn0), al1 = __expf(m1 - mn1);
            float ps0 = 0.f, ps1 = 0.f;
            #pragma unroll
            for (int j = 0; j < 16; j++) {
                s0[j] = __expf(s0[j] - mn0); ps0 += s0[j];
                s1[j] = __expf(s1[j] - mn1); ps1 += s1[j];
            }
            l0 = l0 * al0 + ps0; m0 = mn0;
            l1 = l1 * al1 + ps1; m1 = mn1;
            #pragma unroll
            for (int d = 0; d < 32; d++) { o0[d] *= al0; o1[d] *= al1; }
            #pragma unroll
            for (int j = 0; j < 16; j++) {
                const float* vp = &Vs[(sc * 16 + j) * 32];
                float p0 = s0[j], p1 = s1[j];
                #pragma unroll
                for (int d4 = 0; d4 < 8; d4++) {
                    float4 vv = *(const float4*)(vp + d4 * 4);
                    o0[d4*4+0] = fmaf(p0, vv.x, o0[d4*4+0]);
                    o0[d4*4+1] = fmaf(p0, vv.y, o0[d4*4+1]);
                    o0[d4*4+2] = fmaf(p0, vv.z, o0[d4*4+2]);
                    o0[d4*4+3] = fmaf(p0, vv.w, o0[d4*4+3]);
                    o1[d4*4+0] = fmaf(p1, vv.x, o1[d4*4+0]);
                    o1[d4*4+1] = fmaf(p1, vv.y, o1[d4*4+1]);
                    o1[d4*4+2] = fmaf(p1, vv.z, o1[d4*4+2]);
                    o1[d4*4+3] = fmaf(p1, vv.w, o1[d4*4+3]);
                }
            }
        }
        __syncthreads();
    }

    // epilogue: normalize, add residual, store
    const int n = nh >> 3, h = nh & 7;
    const float inv0 = 1.f / l0, inv1 = 1.f / l1;
    const size_t ob0 = ((size_t)n * WH + r0) * DM + h * DH;
    const size_t ob1 = ((size_t)n * WH + r1) * DM + h * DH;
    #pragma unroll
    for (int d4 = 0; d4 < 8; d4++) {
        float4 x0 = *(const float4*)&X[ob0 + d4 * 4];
        float4 y0;
        y0.x = o0[d4*4+0] * inv0 + x0.x;
        y0.y = o0[d4*4+1] * inv0 + x0.y;
        y0.z = o0[d4*4+2] * inv0 + x0.z;
        y0.w = o0[d4*4+3] * inv0 + x0.w;
        *(float4*)&Out[ob0 + d4 * 4] = y0;
        float4 x1 = *(const float4*)&X[ob1 + d4 * 4];
        float4 y1;
        y1.x = o1[d4*4+0] * inv1 + x1.x;
        y1.y = o1[d4*4+1] * inv1 + x1.y;
        y1.z = o1[d4*4+2] * inv1 + x1.z;
        y1.w = o1[d4*4+3] * inv1 + x1.w;
        *(float4*)&Out[ob1 + d4 * 4] = y1;
    }
}

extern "C" void kernel_launch(void* const* d_in, const int* in_sizes, int n_in,
                              void* d_out, int out_size, void* d_ws, size_t ws_size,
                              hipStream_t stream) {
    const float* x  = (const float*)d_in[0];
    const float* Wq = (const float*)d_in[1];
    const float* bq = (const float*)d_in[2];
    const float* Wk = (const float*)d_in[3];
    const float* bk = (const float*)d_in[4];
    const float* Wv = (const float*)d_in[5];
    const float* bv = (const float*)d_in[6];
    float* out = (float*)d_out;

    const size_t elems = (size_t)NB * WH * DM;   // 4,194,304
    float* Qb = (float*)d_ws;
    float* Kb = Qb + elems;
    float* Vb = Kb + elems;

    dim3 gg(128, 2, 3);     // 16384/128, 256/128, {Q,K,V}
    qkv_gemm<<<gg, 256, 0, stream>>>(x, Wq, bq, Wk, bk, Wv, bv, Qb, Kb, Vb);

    dim3 ga(WH / 256, NB * NHD);   // (8, 64)
    attn<<<ga, 128, 0, stream>>>(Qb, Kb, Vb, x, out);
}

// Round 2
// 813.287 us; speedup vs baseline: 1.2447x; 1.2447x over previous
//
#include <hip/hip_runtime.h>
#include <math.h>

// MHSA fp32, round 2: key-split flash attention for occupancy.
// ws layout: Q at 0, K at +16MB, V at +32MB, each [N*H][WH][32] head-major fp32.
#define WH 2048
#define DM 256
#define NHD 8
#define DH 32
#define NB 8

// ---------------- QKV projection GEMM (unchanged) ----------------
__global__ __launch_bounds__(256) void qkv_gemm(
    const float* __restrict__ X,
    const float* __restrict__ Wq, const float* __restrict__ bq,
    const float* __restrict__ Wk, const float* __restrict__ bk,
    const float* __restrict__ Wv, const float* __restrict__ bv,
    float* __restrict__ Qb, float* __restrict__ Kb, float* __restrict__ Vb)
{
    const float* W; const float* bias; float* Ob;
    if (blockIdx.z == 0)      { W = Wq; bias = bq; Ob = Qb; }
    else if (blockIdx.z == 1) { W = Wk; bias = bk; Ob = Kb; }
    else                      { W = Wv; bias = bv; Ob = Vb; }

    __shared__ float Xt[16][132];
    __shared__ float Ws[16][132];

    const int tid = threadIdx.x;
    const int bm = blockIdx.x * 128;
    const int bn = blockIdx.y * 128;
    const int ty = tid >> 4;
    const int tx = tid & 15;

    float acc[8][8];
    #pragma unroll
    for (int i = 0; i < 8; i++)
        #pragma unroll
        for (int j = 0; j < 8; j++) acc[i][j] = 0.f;

    for (int k0 = 0; k0 < DM; k0 += 16) {
        #pragma unroll
        for (int it = 0; it < 2; it++) {
            int r  = (tid >> 2) + it * 64;
            int kc = (tid & 3) * 4;
            float4 v = *(const float4*)&X[(size_t)(bm + r) * DM + k0 + kc];
            Xt[kc + 0][r] = v.x; Xt[kc + 1][r] = v.y;
            Xt[kc + 2][r] = v.z; Xt[kc + 3][r] = v.w;
        }
        #pragma unroll
        for (int it = 0; it < 2; it++) {
            int kr = (tid >> 5) + it * 8;
            int c4 = (tid & 31) * 4;
            *(float4*)&Ws[kr][c4] = *(const float4*)&W[(size_t)(k0 + kr) * DM + bn + c4];
        }
        __syncthreads();
        #pragma unroll
        for (int kk = 0; kk < 16; kk++) {
            float4 a0 = *(const float4*)&Xt[kk][ty * 8];
            float4 a1 = *(const float4*)&Xt[kk][ty * 8 + 4];
            float4 b0 = *(const float4*)&Ws[kk][tx * 8];
            float4 b1 = *(const float4*)&Ws[kk][tx * 8 + 4];
            float a[8] = {a0.x, a0.y, a0.z, a0.w, a1.x, a1.y, a1.z, a1.w};
            float b[8] = {b0.x, b0.y, b0.z, b0.w, b1.x, b1.y, b1.z, b1.w};
            #pragma unroll
            for (int i = 0; i < 8; i++)
                #pragma unroll
                for (int j = 0; j < 8; j++)
                    acc[i][j] = fmaf(a[i], b[j], acc[i][j]);
        }
        __syncthreads();
    }

    float bv8[8];
    #pragma unroll
    for (int j = 0; j < 8; j++) bv8[j] = bias[bn + tx * 8 + j];

    #pragma unroll
    for (int i = 0; i < 8; i++) {
        int r = bm + ty * 8 + i;
        int n = r >> 11;
        int w = r & (WH - 1);
        #pragma unroll
        for (int j4 = 0; j4 < 2; j4++) {
            int c = bn + tx * 8 + j4 * 4;
            int h = c >> 5, d = c & 31;
            float4 o;
            o.x = acc[i][j4 * 4 + 0] + bv8[j4 * 4 + 0];
            o.y = acc[i][j4 * 4 + 1] + bv8[j4 * 4 + 1];
            o.z = acc[i][j4 * 4 + 2] + bv8[j4 * 4 + 2];
            o.w = acc[i][j4 * 4 + 3] + bv8[j4 * 4 + 3];
            *(float4*)&Ob[(((size_t)n * NHD + h) * WH + w) * DH + d] = o;
        }
    }
}

// ---------------- key-split flash attention ----------------
// Block = 256 threads (4 waves). All 4 waves cover the SAME 128 query rows
// (lane l owns rows q0+l and q0+64+l); wave w owns key slice [w*512,(w+1)*512).
// Each wave stages its own 32-key K/V tile in a private LDS region; partials
// (m, l, o[32]) are combined across waves through LDS at the end.
// smem union: main loop uses 8192 floats (K: [w*1024], V: 4096+[w*1024]);
// combine uses 8704 floats (256 threads x 34).
__global__ __launch_bounds__(256) void attn(
    const float* __restrict__ Qb, const float* __restrict__ Kb,
    const float* __restrict__ Vb, const float* __restrict__ X,
    float* __restrict__ Out)
{
    __shared__ float smem[8704];

    const int tid  = threadIdx.x;
    const int w    = tid >> 6;      // wave id 0..3 = key slice
    const int lane = tid & 63;
    const int nh = blockIdx.y;
    const int q0 = blockIdx.x * 128;
    const size_t base = (size_t)nh * WH * DH;
    const int r0 = q0 + lane, r1 = q0 + 64 + lane;

    float q0r[32], q1r[32];
    #pragma unroll
    for (int d4 = 0; d4 < 8; d4++) {
        float4 a = *(const float4*)&Qb[base + (size_t)r0 * DH + d4 * 4];
        q0r[d4*4+0] = a.x; q0r[d4*4+1] = a.y; q0r[d4*4+2] = a.z; q0r[d4*4+3] = a.w;
        float4 b = *(const float4*)&Qb[base + (size_t)r1 * DH + d4 * 4];
        q1r[d4*4+0] = b.x; q1r[d4*4+1] = b.y; q1r[d4*4+2] = b.z; q1r[d4*4+3] = b.w;
    }

    float o0[32], o1[32];
    #pragma unroll
    for (int d = 0; d < 32; d++) { o0[d] = 0.f; o1[d] = 0.f; }
    float m0 = -INFINITY, m1 = -INFINITY, l0 = 0.f, l1 = 0.f;
    const float scale = 5.65685424949238f;   // sqrt(32), faithful to source

    float* Ksw = &smem[w * 1024];          // this wave's 32x32 K tile
    float* Vsw = &smem[4096 + w * 1024];   // this wave's 32x32 V tile
    const int kbase = w * 512;             // wave's key-slice origin

    for (int kt = 0; kt < 16; kt++) {      // 16 tiles x 32 keys = 512 keys
        // stage this wave's K/V tile: 1024 floats each = 4 float4/lane
        const size_t src = base + (size_t)(kbase + kt * 32) * DH;
        #pragma unroll
        for (int i = 0; i < 4; i++) {
            int f = lane + 64 * i;
            *(float4*)&Ksw[f * 4] = *(const float4*)&Kb[src + f * 4];
            *(float4*)&Vsw[f * 4] = *(const float4*)&Vb[src + f * 4];
        }
        __syncthreads();

        #pragma unroll
        for (int sc = 0; sc < 2; sc++) {   // two 16-key chunks
            float s0[16], s1[16];
            #pragma unroll
            for (int j = 0; j < 16; j++) {
                const float* kp = &Ksw[(sc * 16 + j) * 32];
                float a0 = 0.f, a1 = 0.f;
                #pragma unroll
                for (int d4 = 0; d4 < 8; d4++) {
                    float4 kv = *(const float4*)(kp + d4 * 4);
                    a0 = fmaf(q0r[d4*4+0], kv.x, a0);
                    a0 = fmaf(q0r[d4*4+1], kv.y, a0);
                    a0 = fmaf(q0r[d4*4+2], kv.z, a0);
                    a0 = fmaf(q0r[d4*4+3], kv.w, a0);
                    a1 = fmaf(q1r[d4*4+0], kv.x, a1);
                    a1 = fmaf(q1r[d4*4+1], kv.y, a1);
                    a1 = fmaf(q1r[d4*4+2], kv.z, a1);
                    a1 = fmaf(q1r[d4*4+3], kv.w, a1);
                }
                s0[j] = a0 * scale;
                s1[j] = a1 * scale;
            }
            float cm0 = s0[0], cm1 = s1[0];
            #pragma unroll
            for (int j = 1; j < 16; j++) { cm0 = fmaxf(cm0, s0[j]); cm1 = fmaxf(cm1, s1[j]); }
            float mn0 = fmaxf(m0, cm0), mn1 = fmaxf(m1, cm1);
            float al0 = __expf(m0 - mn0), al1 = __expf(m1 - mn1);
            float ps0 = 0.f, ps1 = 0.f;
            #pragma unroll
            for (int j = 0; j < 16; j++) {
                s0[j] = __expf(s0[j] - mn0); ps0 += s0[j];
                s1[j] = __expf(s1[j] - mn1); ps1 += s1[j];
            }
            l0 = l0 * al0 + ps0; m0 = mn0;
            l1 = l1 * al1 + ps1; m1 = mn1;
            #pragma unroll
            for (int d = 0; d < 32; d++) { o0[d] *= al0; o1[d] *= al1; }
            #pragma unroll
            for (int j = 0; j < 16; j++) {
                const float* vp = &Vsw[(sc * 16 + j) * 32];
                float p0 = s0[j], p1 = s1[j];
                #pragma unroll
                for (int d4 = 0; d4 < 8; d4++) {
                    float4 vv = *(const float4*)(vp + d4 * 4);
                    o0[d4*4+0] = fmaf(p0, vv.x, o0[d4*4+0]);
                    o0[d4*4+1] = fmaf(p0, vv.y, o0[d4*4+1]);
                    o0[d4*4+2] = fmaf(p0, vv.z, o0[d4*4+2]);
                    o0[d4*4+3] = fmaf(p0, vv.w, o0[d4*4+3]);
                    o1[d4*4+0] = fmaf(p1, vv.x, o1[d4*4+0]);
                    o1[d4*4+1] = fmaf(p1, vv.y, o1[d4*4+1]);
                    o1[d4*4+2] = fmaf(p1, vv.z, o1[d4*4+2]);
                    o1[d4*4+3] = fmaf(p1, vv.w, o1[d4*4+3]);
                }
            }
        }
        __syncthreads();
    }

    // ---- cross-wave combine: M=max m_w, O=sum o_w*e^{m_w-M}, L=sum l_w*e^{m_w-M} ----
    const int n = nh >> 3, h = nh & 7;
    #pragma unroll
    for (int p = 0; p < 2; p++) {
        // write this wave's partial for row q0 + p*64 + lane
        float* C = smem;
        int ci = (w * 64 + lane) * 34;
        C[ci]     = p ? m1 : m0;
        C[ci + 1] = p ? l1 : l0;
        #pragma unroll
        for (int d = 0; d < 32; d++) C[ci + 2 + d] = p ? o1[d] : o0[d];
        __syncthreads();

        if (tid < 64) {
            int row = q0 + p * 64 + tid;
            float mw[4], lw[4];
            #pragma unroll
            for (int u = 0; u < 4; u++) {
                mw[u] = C[(u * 64 + tid) * 34];
                lw[u] = C[(u * 64 + tid) * 34 + 1];
            }
            float M = fmaxf(fmaxf(mw[0], mw[1]), fmaxf(mw[2], mw[3]));
            float fac[4], L = 0.f;
            #pragma unroll
            for (int u = 0; u < 4; u++) { fac[u] = __expf(mw[u] - M); L += lw[u] * fac[u]; }
            float inv = 1.f / L;
            const size_t ob = ((size_t)n * WH + row) * DM + h * DH;
            #pragma unroll
            for (int d4 = 0; d4 < 8; d4++) {
                float4 acc4 = {0.f, 0.f, 0.f, 0.f};
                #pragma unroll
                for (int u = 0; u < 4; u++) {
                    const float* op = &C[(u * 64 + tid) * 34 + 2 + d4 * 4];
                    acc4.x = fmaf(op[0], fac[u], acc4.x);
                    acc4.y = fmaf(op[1], fac[u], acc4.y);
                    acc4.z = fmaf(op[2], fac[u], acc4.z);
                    acc4.w = fmaf(op[3], fac[u], acc4.w);
                }
                float4 xr = *(const float4*)&X[ob + d4 * 4];
                float4 y;
                y.x = acc4.x * inv + xr.x;
                y.y = acc4.y * inv + xr.y;
                y.z = acc4.z * inv + xr.z;
                y.w = acc4.w * inv + xr.w;
                *(float4*)&Out[ob + d4 * 4] = y;
            }
        }
        __syncthreads();   // readers done before next phase overwrites C
    }
}

extern "C" void kernel_launch(void* const* d_in, const int* in_sizes, int n_in,
                              void* d_out, int out_size, void* d_ws, size_t ws_size,
                              hipStream_t stream) {
    const float* x  = (const float*)d_in[0];
    const float* Wq = (const float*)d_in[1];
    const float* bq = (const float*)d_in[2];
    const float* Wk = (const float*)d_in[3];
    const float* bk = (const float*)d_in[4];
    const float* Wv = (const float*)d_in[5];
    const float* bv = (const float*)d_in[6];
    float* out = (float*)d_out;

    const size_t elems = (size_t)NB * WH * DM;
    float* Qb = (float*)d_ws;
    float* Kb = Qb + elems;
    float* Vb = Kb + elems;

    dim3 gg(128, 2, 3);
    qkv_gemm<<<gg, 256, 0, stream>>>(x, Wq, bq, Wk, bk, Wv, bv, Qb, Kb, Vb);

    dim3 ga(WH / 128, NB * NHD);   // (16, 64) = 1024 blocks x 4 waves
    attn<<<ga, 256, 0, stream>>>(Qb, Kb, Vb, x, out);
}

// Round 3
// 310.951 us; speedup vs baseline: 3.2554x; 2.6155x over previous
//
#include <hip/hip_runtime.h>
#include <math.h>

// MHSA round 3: bf16 MFMA attention with split-bf16 QK for precision.
// ws (shorts): Qhi[64][2048][32], Qlo, Khi, Klo (same), Vt[64][32][2048] = 40 MB.
#define WH 2048
#define DM 256
#define NHD 8
#define DH 32
#define NB 8

typedef __attribute__((ext_vector_type(8))) short short8;
typedef __attribute__((ext_vector_type(4))) float f32x4;

__device__ __forceinline__ unsigned short bf16_rn(float f) {
    unsigned u = __float_as_uint(f);
    return (unsigned short)((u + 0x8000u) >> 16);
}
__device__ __forceinline__ float bf16_to_f(unsigned short h) {
    return __uint_as_float(((unsigned)h) << 16);
}

// ---------------- QKV projection GEMM (fp32 compute, bf16 split outputs) ----------------
__global__ __launch_bounds__(256) void qkv_gemm(
    const float* __restrict__ X,
    const float* __restrict__ Wq, const float* __restrict__ bq,
    const float* __restrict__ Wk, const float* __restrict__ bk,
    const float* __restrict__ Wv, const float* __restrict__ bv,
    unsigned short* __restrict__ Qhi, unsigned short* __restrict__ Qlo,
    unsigned short* __restrict__ Khi, unsigned short* __restrict__ Klo,
    unsigned short* __restrict__ VtO)
{
    const int z = blockIdx.z;
    const float* W; const float* bias;
    if (z == 0)      { W = Wq; bias = bq; }
    else if (z == 1) { W = Wk; bias = bk; }
    else             { W = Wv; bias = bv; }

    __shared__ float Xt[16][132];
    __shared__ float Ws[16][132];

    const int tid = threadIdx.x;
    const int bm = blockIdx.x * 128;
    const int bn = blockIdx.y * 128;
    const int ty = tid >> 4;
    const int tx = tid & 15;

    float acc[8][8];
    #pragma unroll
    for (int i = 0; i < 8; i++)
        #pragma unroll
        for (int j = 0; j < 8; j++) acc[i][j] = 0.f;

    for (int k0 = 0; k0 < DM; k0 += 16) {
        #pragma unroll
        for (int it = 0; it < 2; it++) {
            int r  = (tid >> 2) + it * 64;
            int kc = (tid & 3) * 4;
            float4 v = *(const float4*)&X[(size_t)(bm + r) * DM + k0 + kc];
            Xt[kc + 0][r] = v.x; Xt[kc + 1][r] = v.y;
            Xt[kc + 2][r] = v.z; Xt[kc + 3][r] = v.w;
        }
        #pragma unroll
        for (int it = 0; it < 2; it++) {
            int kr = (tid >> 5) + it * 8;
            int c4 = (tid & 31) * 4;
            *(float4*)&Ws[kr][c4] = *(const float4*)&W[(size_t)(k0 + kr) * DM + bn + c4];
        }
        __syncthreads();
        #pragma unroll
        for (int kk = 0; kk < 16; kk++) {
            float4 a0 = *(const float4*)&Xt[kk][ty * 8];
            float4 a1 = *(const float4*)&Xt[kk][ty * 8 + 4];
            float4 b0 = *(const float4*)&Ws[kk][tx * 8];
            float4 b1 = *(const float4*)&Ws[kk][tx * 8 + 4];
            float a[8] = {a0.x, a0.y, a0.z, a0.w, a1.x, a1.y, a1.z, a1.w};
            float b[8] = {b0.x, b0.y, b0.z, b0.w, b1.x, b1.y, b1.z, b1.w};
            #pragma unroll
            for (int i = 0; i < 8; i++)
                #pragma unroll
                for (int j = 0; j < 8; j++)
                    acc[i][j] = fmaf(a[i], b[j], acc[i][j]);
        }
        __syncthreads();
    }

    float bv8[8];
    #pragma unroll
    for (int j = 0; j < 8; j++) bv8[j] = bias[bn + tx * 8 + j];

    // rows of this tile never cross an n boundary (bm multiple of 128)
    const int n  = bm >> 11;
    const int wb = (bm & (WH - 1)) + ty * 8;
    const int c0 = bn + tx * 8;
    const int h  = c0 >> 5;
    const int db = c0 & 31;          // multiple of 8

    if (z == 2) {
        // V: store transposed bf16: Vt[(n*8+h)*32 + d][w]
        #pragma unroll
        for (int j = 0; j < 8; j++) {
            const int d = db + j;
            short8 t;
            #pragma unroll
            for (int i = 0; i < 8; i++) t[i] = (short)bf16_rn(acc[i][j] + bv8[j]);
            *(short8*)&VtO[((size_t)((n * NHD + h) * DH + d)) * WH + wb] = t;
        }
    } else {
        unsigned short* Ahi = (z == 0) ? Qhi : Khi;
        unsigned short* Alo = (z == 0) ? Qlo : Klo;
        #pragma unroll
        for (int i = 0; i < 8; i++) {
            short8 hi8, lo8;
            #pragma unroll
            for (int j = 0; j < 8; j++) {
                float v = acc[i][j] + bv8[j];
                unsigned short hb = bf16_rn(v);
                hi8[j] = (short)hb;
                lo8[j] = (short)bf16_rn(v - bf16_to_f(hb));
            }
            const size_t off = ((size_t)(n * NHD + h) * WH + wb + i) * DH + db;
            *(short8*)&Ahi[off] = hi8;
            *(short8*)&Alo[off] = lo8;
        }
    }
}

// ---------------- MFMA flash attention ----------------
// Block = 256 threads (4 waves). Wave w owns 16 q-rows (q0 + w*16 + lane&15).
// Loop over 64 tiles of 32 keys: K/V staged in double-buffered LDS (shared),
// S = split-bf16 QK^T (3 MFMAs per 16-key group), transpose S through
// per-wave LDS into row-layout, fp32 online softmax, P packed directly into
// the PV A-fragment, PV = 2 MFMAs.
__global__ __launch_bounds__(256) void attn(
    const unsigned short* __restrict__ Qhi, const unsigned short* __restrict__ Qlo,
    const unsigned short* __restrict__ Khi, const unsigned short* __restrict__ Klo,
    const unsigned short* __restrict__ Vt,  const float* __restrict__ X,
    float* __restrict__ Out)
{
    __shared__ __align__(16) unsigned short Ks [2][32 * 32];
    __shared__ __align__(16) unsigned short Kls[2][32 * 32];
    __shared__ __align__(16) unsigned short Vs [2][32 * 32];   // [d][key]
    __shared__ __align__(16) float Srow[4][16 * 36];           // per-wave, stride 36
    __shared__ __align__(16) float Abr[4][16];                 // per-wave broadcast

    const int tid  = threadIdx.x;
    const int w    = tid >> 6;
    const int lane = tid & 63;
    const int col  = lane & 15;
    const int quad = lane >> 4;
    const int nh   = blockIdx.y;
    const int q0   = blockIdx.x * 64;

    const size_t kbase = (size_t)nh * WH * DH;   // Qhi/Qlo/Khi/Klo element base
    const size_t vbase = (size_t)nh * DH * WH;   // Vt element base

    // Q fragments (A-layout: m=col, k=quad*8+j)
    const int qrow = q0 + w * 16 + col;
    const short8 qhi = *(const short8*)&Qhi[kbase + (size_t)qrow * DH + quad * 8];
    const short8 qlo = *(const short8*)&Qlo[kbase + (size_t)qrow * DH + quad * 8];

    f32x4 o0 = {0.f, 0.f, 0.f, 0.f}, o1 = {0.f, 0.f, 0.f, 0.f};
    float m_run = -INFINITY, l_run = 0.f;
    const float scale = 5.65685424949238f;   // sqrt(32), faithful to source

    // staging map: thread t covers 8 B of each 2 KB tile
    const int srow_ = tid >> 3;        // key (for K) or d (for Vt)
    const int sc4   = (tid & 7) * 4;   // 4-short chunk

    { // preload tile 0
        *(uint2*)&Ks [0][srow_ * 32 + sc4] = *(const uint2*)&Khi[kbase + (size_t)srow_ * DH + sc4];
        *(uint2*)&Kls[0][srow_ * 32 + sc4] = *(const uint2*)&Klo[kbase + (size_t)srow_ * DH + sc4];
        *(uint2*)&Vs [0][srow_ * 32 + sc4] = *(const uint2*)&Vt [vbase + (size_t)srow_ * WH + sc4];
    }
    __syncthreads();

    for (int kt = 0; kt < 64; kt++) {
        const int b = kt & 1;
        uint2 nk, nkl, nv;
        if (kt < 63) {   // issue next-tile global loads early
            const size_t ko = kbase + ((size_t)(kt + 1) * 32 + srow_) * DH + sc4;
            nk  = *(const uint2*)&Khi[ko];
            nkl = *(const uint2*)&Klo[ko];
            nv  = *(const uint2*)&Vt [vbase + (size_t)srow_ * WH + (kt + 1) * 32 + sc4];
        }

        // K fragments (B-layout: n=col(+16), k=quad*8+j over dim)
        const short8 kh0 = *(const short8*)&Ks [b][(col     ) * 32 + quad * 8];
        const short8 kh1 = *(const short8*)&Ks [b][(col + 16) * 32 + quad * 8];
        const short8 kl0 = *(const short8*)&Kls[b][(col     ) * 32 + quad * 8];
        const short8 kl1 = *(const short8*)&Kls[b][(col + 16) * 32 + quad * 8];

        f32x4 s0 = {0.f, 0.f, 0.f, 0.f}, s1 = {0.f, 0.f, 0.f, 0.f};
        s0 = __builtin_amdgcn_mfma_f32_16x16x32_bf16(qlo, kh0, s0, 0, 0, 0);
        s0 = __builtin_amdgcn_mfma_f32_16x16x32_bf16(qhi, kl0, s0, 0, 0, 0);
        s0 = __builtin_amdgcn_mfma_f32_16x16x32_bf16(qhi, kh0, s0, 0, 0, 0);
        s1 = __builtin_amdgcn_mfma_f32_16x16x32_bf16(qlo, kh1, s1, 0, 0, 0);
        s1 = __builtin_amdgcn_mfma_f32_16x16x32_bf16(qhi, kl1, s1, 0, 0, 0);
        s1 = __builtin_amdgcn_mfma_f32_16x16x32_bf16(qhi, kh1, s1, 0, 0, 0);

        // transpose S: C-layout (row=quad*4+r, key=col/+16) -> row-major LDS
        #pragma unroll
        for (int r = 0; r < 4; r++) {
            Srow[w][(quad * 4 + r) * 36 + col     ] = s0[r];
            Srow[w][(quad * 4 + r) * 36 + col + 16] = s1[r];
        }
        // read back: this lane's row = col, keys quad*8 + 0..7 (wave-synchronous)
        const f32x4 ra = *(const f32x4*)&Srow[w][col * 36 + quad * 8];
        const f32x4 rb = *(const f32x4*)&Srow[w][col * 36 + quad * 8 + 4];
        float sv[8] = {ra[0], ra[1], ra[2], ra[3], rb[0], rb[1], rb[2], rb[3]};
        #pragma unroll
        for (int j = 0; j < 8; j++) sv[j] *= scale;

        float mx = sv[0];
        #pragma unroll
        for (int j = 1; j < 8; j++) mx = fmaxf(mx, sv[j]);
        mx = fmaxf(mx, __shfl_xor(mx, 16));
        mx = fmaxf(mx, __shfl_xor(mx, 32));
        const float mnew  = fmaxf(m_run, mx);
        const float alpha = __expf(m_run - mnew);

        float p[8], ps = 0.f;
        #pragma unroll
        for (int j = 0; j < 8; j++) { p[j] = __expf(sv[j] - mnew); ps += p[j]; }
        ps += __shfl_xor(ps, 16);
        ps += __shfl_xor(ps, 32);
        l_run = l_run * alpha + ps;
        m_run = mnew;

        // P -> bf16 A-fragment (m=col=row, k=quad*8+j=key): already in place
        short8 pf;
        #pragma unroll
        for (int j = 0; j < 8; j++) pf[j] = (short)bf16_rn(p[j]);

        // broadcast alpha to C-layout rows
        if (lane < 16) Abr[w][lane] = alpha;
        const f32x4 av = *(const f32x4*)&Abr[w][quad * 4];
        #pragma unroll
        for (int r = 0; r < 4; r++) { o0[r] *= av[r]; o1[r] *= av[r]; }

        // V fragments (B-layout: n=col(+16)=d, k=quad*8+j=key) from Vt[d][key]
        const short8 v0 = *(const short8*)&Vs[b][(col     ) * 32 + quad * 8];
        const short8 v1 = *(const short8*)&Vs[b][(col + 16) * 32 + quad * 8];
        o0 = __builtin_amdgcn_mfma_f32_16x16x32_bf16(pf, v0, o0, 0, 0, 0);
        o1 = __builtin_amdgcn_mfma_f32_16x16x32_bf16(pf, v1, o1, 0, 0, 0);

        if (kt < 63) {   // commit next tile to the other buffer
            *(uint2*)&Ks [b ^ 1][srow_ * 32 + sc4] = nk;
            *(uint2*)&Kls[b ^ 1][srow_ * 32 + sc4] = nkl;
            *(uint2*)&Vs [b ^ 1][srow_ * 32 + sc4] = nv;
        }
        __syncthreads();
    }

    // epilogue: broadcast 1/l to C-layout rows, add residual, store
    if (lane < 16) Abr[w][lane] = 1.f / l_run;
    const f32x4 lv = *(const f32x4*)&Abr[w][quad * 4];
    const int n = nh >> 3, h = nh & 7;
    #pragma unroll
    for (int r = 0; r < 4; r++) {
        const int row = q0 + w * 16 + quad * 4 + r;
        const size_t a0 = ((size_t)n * WH + row) * DM + h * DH + col;
        Out[a0]      = o0[r] * lv[r] + X[a0];
        Out[a0 + 16] = o1[r] * lv[r] + X[a0 + 16];
    }
}

extern "C" void kernel_launch(void* const* d_in, const int* in_sizes, int n_in,
                              void* d_out, int out_size, void* d_ws, size_t ws_size,
                              hipStream_t stream) {
    const float* x  = (const float*)d_in[0];
    const float* Wq = (const float*)d_in[1];
    const float* bq = (const float*)d_in[2];
    const float* Wk = (const float*)d_in[3];
    const float* bk = (const float*)d_in[4];
    const float* Wv = (const float*)d_in[5];
    const float* bv = (const float*)d_in[6];
    float* out = (float*)d_out;

    const size_t elems = (size_t)NB * WH * DM;   // 4,194,304 per array
    unsigned short* Qhi = (unsigned short*)d_ws;
    unsigned short* Qlo = Qhi + elems;
    unsigned short* Khi = Qlo + elems;
    unsigned short* Klo = Khi + elems;
    unsigned short* Vt  = Klo + elems;

    dim3 gg(128, 2, 3);
    qkv_gemm<<<gg, 256, 0, stream>>>(x, Wq, bq, Wk, bk, Wv, bv,
                                     Qhi, Qlo, Khi, Klo, Vt);

    dim3 ga(WH / 64, NB * NHD);   // (32, 64) = 2048 blocks x 4 waves
    attn<<<ga, 256, 0, stream>>>(Qhi, Qlo, Khi, Klo, Vt, x, out);
}

// Round 4
// 272.403 us; speedup vs baseline: 3.7160x; 1.1415x over previous
//
#include <hip/hip_runtime.h>
#include <math.h>

// MHSA round 4: MFMA qkv projections (split-bf16) + bank-conflict-free attn LDS.
// ws (shorts): Qhi,Qlo,Khi,Klo [64][2048][32]; Vt [64][32][2048]; WThi/WTlo [3][256][256].
#define WH 2048
#define DM 256
#define NHD 8
#define DH 32
#define NB 8

typedef __attribute__((ext_vector_type(8))) short short8;
typedef __attribute__((ext_vector_type(4))) float f32x4;

__device__ __forceinline__ unsigned short bf16_rn(float f) {
    unsigned u = __float_as_uint(f);
    return (unsigned short)((u + 0x8000u) >> 16);
}
__device__ __forceinline__ float bf16_to_f(unsigned short h) {
    return __uint_as_float(((unsigned)h) << 16);
}

// ---------------- W prep: transpose + split to bf16 hi/lo ----------------
// WT[z][n][k], z in {q,k,v}. Grid (16, 3) x 256 threads.
__global__ __launch_bounds__(256) void wprep(
    const float* __restrict__ Wq, const float* __restrict__ Wk,
    const float* __restrict__ Wv,
    unsigned short* __restrict__ WThi, unsigned short* __restrict__ WTlo)
{
    const int z = blockIdx.y;
    const float* W = (z == 0) ? Wq : ((z == 1) ? Wk : Wv);
    const size_t zoff = (size_t)z * DM * DM;
    const int tg = blockIdx.x * 256 + threadIdx.x;   // 0..4095
    #pragma unroll
    for (int j = 0; j < 4; j++) {
        const int f = tg + j * 4096;         // float4 index, 16384 per mat
        const int k  = f >> 6;               // 64 float4 per row
        const int n0 = (f & 63) * 4;
        float4 v = *(const float4*)&W[(size_t)k * DM + n0];
        float vv[4] = {v.x, v.y, v.z, v.w};
        #pragma unroll
        for (int i = 0; i < 4; i++) {
            unsigned short hb = bf16_rn(vv[i]);
            WThi[zoff + (size_t)(n0 + i) * DM + k] = hb;
            WTlo[zoff + (size_t)(n0 + i) * DM + k] = bf16_rn(vv[i] - bf16_to_f(hb));
        }
    }
}

// ---------------- QKV projection: split-bf16 MFMA GEMM ----------------
// C(16384x256) = X @ W + b. Block 256 thr = 4 waves (2x2), tile 128x128, BK=32.
// Wave computes 64x64 via 4x4 fragments of 16x16x32, 3 MFMAs per fragment pair.
#define ASTR 40   // LDS row stride in shorts (80 B = 16B-aligned, bank-friendly)
__global__ __launch_bounds__(256) void qkv_mfma(
    const float* __restrict__ X,
    const unsigned short* __restrict__ WThi, const unsigned short* __restrict__ WTlo,
    const float* __restrict__ bq, const float* __restrict__ bk, const float* __restrict__ bv,
    unsigned short* __restrict__ Qhi, unsigned short* __restrict__ Qlo,
    unsigned short* __restrict__ Khi, unsigned short* __restrict__ Klo,
    unsigned short* __restrict__ Vt)
{
    __shared__ __align__(16) unsigned short Ah[128 * ASTR];
    __shared__ __align__(16) unsigned short Al[128 * ASTR];
    __shared__ __align__(16) unsigned short Bh[128 * ASTR];
    __shared__ __align__(16) unsigned short Bl[128 * ASTR];

    const int z = blockIdx.z;
    const float* bias = (z == 0) ? bq : ((z == 1) ? bk : bv);
    const size_t zoff = (size_t)z * DM * DM;

    const int tid  = threadIdx.x;
    const int w    = tid >> 6;
    const int lane = tid & 63;
    const int col  = lane & 15;
    const int quad = lane >> 4;
    const int wr = w >> 1, wc = w & 1;
    const int bm = blockIdx.x * 128;
    const int bn = blockIdx.y * 128;

    f32x4 acc[4][4];
    #pragma unroll
    for (int mi = 0; mi < 4; mi++)
        #pragma unroll
        for (int ni = 0; ni < 4; ni++) acc[mi][ni] = (f32x4){0.f, 0.f, 0.f, 0.f};

    for (int kb = 0; kb < 8; kb++) {
        const int k0 = kb * 32;
        // stage A: X[bm..+127][k0..+31] fp32 -> hi/lo bf16 LDS
        {
            const int r = tid >> 1;
            #pragma unroll
            for (int i = 0; i < 4; i++) {
                const int fc = (tid & 1) * 4 + i;
                float4 v = *(const float4*)&X[(size_t)(bm + r) * DM + k0 + fc * 4];
                float vv[4] = {v.x, v.y, v.z, v.w};
                unsigned short h4[4], l4[4];
                #pragma unroll
                for (int e = 0; e < 4; e++) {
                    h4[e] = bf16_rn(vv[e]);
                    l4[e] = bf16_rn(vv[e] - bf16_to_f(h4[e]));
                }
                unsigned hw0 = (unsigned)h4[0] | ((unsigned)h4[1] << 16);
                unsigned hw1 = (unsigned)h4[2] | ((unsigned)h4[3] << 16);
                unsigned lw0 = (unsigned)l4[0] | ((unsigned)l4[1] << 16);
                unsigned lw1 = (unsigned)l4[2] | ((unsigned)l4[3] << 16);
                *(uint2*)&Ah[r * ASTR + fc * 4] = make_uint2(hw0, hw1);
                *(uint2*)&Al[r * ASTR + fc * 4] = make_uint2(lw0, lw1);
            }
        }
        // stage B: WT[z][bn..+127][k0..+31] bf16 copy
        {
            const int n = tid >> 1;
            #pragma unroll
            for (int i = 0; i < 2; i++) {
                const int s8 = (tid & 1) * 2 + i;
                *(short8*)&Bh[n * ASTR + s8 * 8] =
                    *(const short8*)&WThi[zoff + (size_t)(bn + n) * DM + k0 + s8 * 8];
                *(short8*)&Bl[n * ASTR + s8 * 8] =
                    *(const short8*)&WTlo[zoff + (size_t)(bn + n) * DM + k0 + s8 * 8];
            }
        }
        __syncthreads();

        short8 ah[4], al[4], bh[4], bl[4];
        #pragma unroll
        for (int mi = 0; mi < 4; mi++) {
            const int row = wr * 64 + mi * 16 + col;
            ah[mi] = *(const short8*)&Ah[row * ASTR + quad * 8];
            al[mi] = *(const short8*)&Al[row * ASTR + quad * 8];
        }
        #pragma unroll
        for (int ni = 0; ni < 4; ni++) {
            const int nn = wc * 64 + ni * 16 + col;
            bh[ni] = *(const short8*)&Bh[nn * ASTR + quad * 8];
            bl[ni] = *(const short8*)&Bl[nn * ASTR + quad * 8];
        }
        #pragma unroll
        for (int mi = 0; mi < 4; mi++)
            #pragma unroll
            for (int ni = 0; ni < 4; ni++) {
                acc[mi][ni] = __builtin_amdgcn_mfma_f32_16x16x32_bf16(al[mi], bh[ni], acc[mi][ni], 0, 0, 0);
                acc[mi][ni] = __builtin_amdgcn_mfma_f32_16x16x32_bf16(ah[mi], bl[ni], acc[mi][ni], 0, 0, 0);
                acc[mi][ni] = __builtin_amdgcn_mfma_f32_16x16x32_bf16(ah[mi], bh[ni], acc[mi][ni], 0, 0, 0);
            }
        __syncthreads();
    }

    // epilogue: bias, then scatter to split Q/K or transposed V (bf16)
    #pragma unroll
    for (int mi = 0; mi < 4; mi++) {
        #pragma unroll
        for (int ni = 0; ni < 4; ni++) {
            const int coln = bn + wc * 64 + ni * 16 + col;
            const float bb = bias[coln];
            const int h = coln >> 5, d = coln & 31;
            #pragma unroll
            for (int r = 0; r < 4; r++) {
                const int gr = bm + wr * 64 + mi * 16 + quad * 4 + r;
                const int n = gr >> 11, wq = gr & (WH - 1);
                const float v = acc[mi][ni][r] + bb;
                if (z == 2) {
                    Vt[((size_t)(n * NHD + h) * DH + d) * WH + wq] = bf16_rn(v);
                } else {
                    unsigned short* Thi = (z == 0) ? Qhi : Khi;
                    unsigned short* Tlo = (z == 0) ? Qlo : Klo;
                    const size_t off = ((size_t)(n * NHD + h) * WH + wq) * DH + d;
                    const unsigned short hb = bf16_rn(v);
                    Thi[off] = hb;
                    Tlo[off] = bf16_rn(v - bf16_to_f(hb));
                }
            }
        }
    }
}

// ---------------- MFMA flash attention (stride-40 LDS, conflict-free) ----------------
#define KSTR 40   // K/V LDS row stride in shorts
__global__ __launch_bounds__(256) void attn(
    const unsigned short* __restrict__ Qhi, const unsigned short* __restrict__ Qlo,
    const unsigned short* __restrict__ Khi, const unsigned short* __restrict__ Klo,
    const unsigned short* __restrict__ Vt,  const float* __restrict__ X,
    float* __restrict__ Out)
{
    __shared__ __align__(16) unsigned short Ks [2][32 * KSTR];
    __shared__ __align__(16) unsigned short Kls[2][32 * KSTR];
    __shared__ __align__(16) unsigned short Vs [2][32 * KSTR];   // [d][key]
    __shared__ __align__(16) float Srow[4][16 * 36];             // per-wave, stride 36
    __shared__ __align__(16) float Abr[4][16];

    const int tid  = threadIdx.x;
    const int w    = tid >> 6;
    const int lane = tid & 63;
    const int col  = lane & 15;
    const int quad = lane >> 4;
    const int nh   = blockIdx.y;
    const int q0   = blockIdx.x * 64;

    const size_t kbase = (size_t)nh * WH * DH;
    const size_t vbase = (size_t)nh * DH * WH;

    const int qrow = q0 + w * 16 + col;
    const short8 qhi = *(const short8*)&Qhi[kbase + (size_t)qrow * DH + quad * 8];
    const short8 qlo = *(const short8*)&Qlo[kbase + (size_t)qrow * DH + quad * 8];

    f32x4 o0 = {0.f, 0.f, 0.f, 0.f}, o1 = {0.f, 0.f, 0.f, 0.f};
    float m_run = -INFINITY, l_run = 0.f;
    const float scale = 5.65685424949238f;   // sqrt(32), faithful to source

    const int srow_ = tid >> 3;        // key (K) / d (Vt)
    const int sc4   = (tid & 7) * 4;

    { // preload tile 0
        *(uint2*)&Ks [0][srow_ * KSTR + sc4] = *(const uint2*)&Khi[kbase + (size_t)srow_ * DH + sc4];
        *(uint2*)&Kls[0][srow_ * KSTR + sc4] = *(const uint2*)&Klo[kbase + (size_t)srow_ * DH + sc4];
        *(uint2*)&Vs [0][srow_ * KSTR + sc4] = *(const uint2*)&Vt [vbase + (size_t)srow_ * WH + sc4];
    }
    __syncthreads();

    for (int kt = 0; kt < 64; kt++) {
        const int b = kt & 1;
        uint2 nk, nkl, nv;
        if (kt < 63) {
            const size_t ko = kbase + ((size_t)(kt + 1) * 32 + srow_) * DH + sc4;
            nk  = *(const uint2*)&Khi[ko];
            nkl = *(const uint2*)&Klo[ko];
            nv  = *(const uint2*)&Vt [vbase + (size_t)srow_ * WH + (kt + 1) * 32 + sc4];
        }

        const short8 kh0 = *(const short8*)&Ks [b][(col     ) * KSTR + quad * 8];
        const short8 kh1 = *(const short8*)&Ks [b][(col + 16) * KSTR + quad * 8];
        const short8 kl0 = *(const short8*)&Kls[b][(col     ) * KSTR + quad * 8];
        const short8 kl1 = *(const short8*)&Kls[b][(col + 16) * KSTR + quad * 8];

        f32x4 s0 = {0.f, 0.f, 0.f, 0.f}, s1 = {0.f, 0.f, 0.f, 0.f};
        s0 = __builtin_amdgcn_mfma_f32_16x16x32_bf16(qlo, kh0, s0, 0, 0, 0);
        s0 = __builtin_amdgcn_mfma_f32_16x16x32_bf16(qhi, kl0, s0, 0, 0, 0);
        s0 = __builtin_amdgcn_mfma_f32_16x16x32_bf16(qhi, kh0, s0, 0, 0, 0);
        s1 = __builtin_amdgcn_mfma_f32_16x16x32_bf16(qlo, kh1, s1, 0, 0, 0);
        s1 = __builtin_amdgcn_mfma_f32_16x16x32_bf16(qhi, kl1, s1, 0, 0, 0);
        s1 = __builtin_amdgcn_mfma_f32_16x16x32_bf16(qhi, kh1, s1, 0, 0, 0);

        #pragma unroll
        for (int r = 0; r < 4; r++) {
            Srow[w][(quad * 4 + r) * 36 + col     ] = s0[r];
            Srow[w][(quad * 4 + r) * 36 + col + 16] = s1[r];
        }
        const f32x4 ra = *(const f32x4*)&Srow[w][col * 36 + quad * 8];
        const f32x4 rb = *(const f32x4*)&Srow[w][col * 36 + quad * 8 + 4];
        float sv[8] = {ra[0], ra[1], ra[2], ra[3], rb[0], rb[1], rb[2], rb[3]};
        #pragma unroll
        for (int j = 0; j < 8; j++) sv[j] *= scale;

        float mx = sv[0];
        #pragma unroll
        for (int j = 1; j < 8; j++) mx = fmaxf(mx, sv[j]);
        mx = fmaxf(mx, __shfl_xor(mx, 16));
        mx = fmaxf(mx, __shfl_xor(mx, 32));
        const float mnew  = fmaxf(m_run, mx);
        const float alpha = __expf(m_run - mnew);

        float p[8], ps = 0.f;
        #pragma unroll
        for (int j = 0; j < 8; j++) { p[j] = __expf(sv[j] - mnew); ps += p[j]; }
        ps += __shfl_xor(ps, 16);
        ps += __shfl_xor(ps, 32);
        l_run = l_run * alpha + ps;
        m_run = mnew;

        short8 pf;
        #pragma unroll
        for (int j = 0; j < 8; j++) pf[j] = (short)bf16_rn(p[j]);

        if (lane < 16) Abr[w][lane] = alpha;
        const f32x4 av = *(const f32x4*)&Abr[w][quad * 4];
        #pragma unroll
        for (int r = 0; r < 4; r++) { o0[r] *= av[r]; o1[r] *= av[r]; }

        const short8 v0 = *(const short8*)&Vs[b][(col     ) * KSTR + quad * 8];
        const short8 v1 = *(const short8*)&Vs[b][(col + 16) * KSTR + quad * 8];
        o0 = __builtin_amdgcn_mfma_f32_16x16x32_bf16(pf, v0, o0, 0, 0, 0);
        o1 = __builtin_amdgcn_mfma_f32_16x16x32_bf16(pf, v1, o1, 0, 0, 0);

        if (kt < 63) {
            *(uint2*)&Ks [b ^ 1][srow_ * KSTR + sc4] = nk;
            *(uint2*)&Kls[b ^ 1][srow_ * KSTR + sc4] = nkl;
            *(uint2*)&Vs [b ^ 1][srow_ * KSTR + sc4] = nv;
        }
        __syncthreads();
    }

    if (lane < 16) Abr[w][lane] = 1.f / l_run;
    const f32x4 lv = *(const f32x4*)&Abr[w][quad * 4];
    const int n = nh >> 3, h = nh & 7;
    #pragma unroll
    for (int r = 0; r < 4; r++) {
        const int row = q0 + w * 16 + quad * 4 + r;
        const size_t a0 = ((size_t)n * WH + row) * DM + h * DH + col;
        Out[a0]      = o0[r] * lv[r] + X[a0];
        Out[a0 + 16] = o1[r] * lv[r] + X[a0 + 16];
    }
}

extern "C" void kernel_launch(void* const* d_in, const int* in_sizes, int n_in,
                              void* d_out, int out_size, void* d_ws, size_t ws_size,
                              hipStream_t stream) {
    const float* x  = (const float*)d_in[0];
    const float* Wq = (const float*)d_in[1];
    const float* bq = (const float*)d_in[2];
    const float* Wk = (const float*)d_in[3];
    const float* bk = (const float*)d_in[4];
    const float* Wv = (const float*)d_in[5];
    const float* bv = (const float*)d_in[6];
    float* out = (float*)d_out;

    const size_t elems = (size_t)NB * WH * DM;   // 4,194,304
    unsigned short* Qhi = (unsigned short*)d_ws;
    unsigned short* Qlo  = Qhi + elems;
    unsigned short* Khi  = Qlo + elems;
    unsigned short* Klo  = Khi + elems;
    unsigned short* Vt   = Klo + elems;
    unsigned short* WThi = Vt  + elems;
    unsigned short* WTlo = WThi + (size_t)3 * DM * DM;

    dim3 gw(16, 3);
    wprep<<<gw, 256, 0, stream>>>(Wq, Wk, Wv, WThi, WTlo);

    dim3 gg(128, 2, 3);
    qkv_mfma<<<gg, 256, 0, stream>>>(x, WThi, WTlo, bq, bk, bv,
                                     Qhi, Qlo, Khi, Klo, Vt);

    dim3 ga(WH / 64, NB * NHD);   // (32, 64)
    attn<<<ga, 256, 0, stream>>>(Qhi, Qlo, Khi, Klo, Vt, x, out);
}

// Round 5
// 272.339 us; speedup vs baseline: 3.7169x; 1.0002x over previous
//
#include <hip/hip_runtime.h>
#include <math.h>

// MHSA round 5: transpose-free MFMA attention (S^T = K·Q^T, O^T = V^T·P^T)
// + vectorized qkv epilogue. Q pre-scaled by sqrt(32)*log2(e); attn uses exp2.
// ws (shorts): Qhi,Qlo,Khi,Klo [64][2048][32]; Vt [64][32][2048]; WThi/WTlo [3][256][256].
#define WH 2048
#define DM 256
#define NHD 8
#define DH 32
#define NB 8

typedef __attribute__((ext_vector_type(8))) short short8;
typedef __attribute__((ext_vector_type(4))) short short4v;
typedef __attribute__((ext_vector_type(4))) float f32x4;

__device__ __forceinline__ unsigned short bf16_rn(float f) {
    unsigned u = __float_as_uint(f);
    return (unsigned short)((u + 0x8000u) >> 16);
}
__device__ __forceinline__ float bf16_to_f(unsigned short h) {
    return __uint_as_float(((unsigned)h) << 16);
}

// ---------------- W prep: transpose + split to bf16 hi/lo ----------------
__global__ __launch_bounds__(256) void wprep(
    const float* __restrict__ Wq, const float* __restrict__ Wk,
    const float* __restrict__ Wv,
    unsigned short* __restrict__ WThi, unsigned short* __restrict__ WTlo)
{
    const int z = blockIdx.y;
    const float* W = (z == 0) ? Wq : ((z == 1) ? Wk : Wv);
    const size_t zoff = (size_t)z * DM * DM;
    const int tg = blockIdx.x * 256 + threadIdx.x;
    #pragma unroll
    for (int j = 0; j < 4; j++) {
        const int f = tg + j * 4096;
        const int k  = f >> 6;
        const int n0 = (f & 63) * 4;
        float4 v = *(const float4*)&W[(size_t)k * DM + n0];
        float vv[4] = {v.x, v.y, v.z, v.w};
        #pragma unroll
        for (int i = 0; i < 4; i++) {
            unsigned short hb = bf16_rn(vv[i]);
            WThi[zoff + (size_t)(n0 + i) * DM + k] = hb;
            WTlo[zoff + (size_t)(n0 + i) * DM + k] = bf16_rn(vv[i] - bf16_to_f(hb));
        }
    }
}

// ---------------- QKV projection: split-bf16 MFMA GEMM ----------------
#define ASTR 40
__global__ __launch_bounds__(256) void qkv_mfma(
    const float* __restrict__ X,
    const unsigned short* __restrict__ WThi, const unsigned short* __restrict__ WTlo,
    const float* __restrict__ bq, const float* __restrict__ bk, const float* __restrict__ bv,
    unsigned short* __restrict__ Qhi, unsigned short* __restrict__ Qlo,
    unsigned short* __restrict__ Khi, unsigned short* __restrict__ Klo,
    unsigned short* __restrict__ Vt)
{
    __shared__ __align__(16) char arena[40960];
    unsigned short* Ah = (unsigned short*)arena;
    unsigned short* Al = Ah + 128 * ASTR;
    unsigned short* Bh = Al + 128 * ASTR;
    unsigned short* Bl = Bh + 128 * ASTR;

    const int z = blockIdx.z;
    const float* bias = (z == 0) ? bq : ((z == 1) ? bk : bv);
    const size_t zoff = (size_t)z * DM * DM;

    const int tid  = threadIdx.x;
    const int w    = tid >> 6;
    const int lane = tid & 63;
    const int col  = lane & 15;
    const int quad = lane >> 4;
    const int wr = w >> 1, wc = w & 1;
    const int bm = blockIdx.x * 128;
    const int bn = blockIdx.y * 128;

    f32x4 acc[4][4];
    #pragma unroll
    for (int mi = 0; mi < 4; mi++)
        #pragma unroll
        for (int ni = 0; ni < 4; ni++) acc[mi][ni] = (f32x4){0.f, 0.f, 0.f, 0.f};

    for (int kb = 0; kb < 8; kb++) {
        const int k0 = kb * 32;
        {   // stage A: X fp32 -> hi/lo bf16
            const int r = tid >> 1;
            #pragma unroll
            for (int i = 0; i < 4; i++) {
                const int fc = (tid & 1) * 4 + i;
                float4 v = *(const float4*)&X[(size_t)(bm + r) * DM + k0 + fc * 4];
                float vv[4] = {v.x, v.y, v.z, v.w};
                unsigned short h4[4], l4[4];
                #pragma unroll
                for (int e = 0; e < 4; e++) {
                    h4[e] = bf16_rn(vv[e]);
                    l4[e] = bf16_rn(vv[e] - bf16_to_f(h4[e]));
                }
                *(uint2*)&Ah[r * ASTR + fc * 4] =
                    make_uint2((unsigned)h4[0] | ((unsigned)h4[1] << 16),
                               (unsigned)h4[2] | ((unsigned)h4[3] << 16));
                *(uint2*)&Al[r * ASTR + fc * 4] =
                    make_uint2((unsigned)l4[0] | ((unsigned)l4[1] << 16),
                               (unsigned)l4[2] | ((unsigned)l4[3] << 16));
            }
        }
        {   // stage B: WT bf16 copy
            const int n = tid >> 1;
            #pragma unroll
            for (int i = 0; i < 2; i++) {
                const int s8 = (tid & 1) * 2 + i;
                *(short8*)&Bh[n * ASTR + s8 * 8] =
                    *(const short8*)&WThi[zoff + (size_t)(bn + n) * DM + k0 + s8 * 8];
                *(short8*)&Bl[n * ASTR + s8 * 8] =
                    *(const short8*)&WTlo[zoff + (size_t)(bn + n) * DM + k0 + s8 * 8];
            }
        }
        __syncthreads();

        short8 ah[4], al[4], bh[4], bl[4];
        #pragma unroll
        for (int mi = 0; mi < 4; mi++) {
            const int row = wr * 64 + mi * 16 + col;
            ah[mi] = *(const short8*)&Ah[row * ASTR + quad * 8];
            al[mi] = *(const short8*)&Al[row * ASTR + quad * 8];
        }
        #pragma unroll
        for (int ni = 0; ni < 4; ni++) {
            const int nn = wc * 64 + ni * 16 + col;
            bh[ni] = *(const short8*)&Bh[nn * ASTR + quad * 8];
            bl[ni] = *(const short8*)&Bl[nn * ASTR + quad * 8];
        }
        #pragma unroll
        for (int mi = 0; mi < 4; mi++)
            #pragma unroll
            for (int ni = 0; ni < 4; ni++) {
                acc[mi][ni] = __builtin_amdgcn_mfma_f32_16x16x32_bf16(al[mi], bh[ni], acc[mi][ni], 0, 0, 0);
                acc[mi][ni] = __builtin_amdgcn_mfma_f32_16x16x32_bf16(ah[mi], bl[ni], acc[mi][ni], 0, 0, 0);
                acc[mi][ni] = __builtin_amdgcn_mfma_f32_16x16x32_bf16(ah[mi], bh[ni], acc[mi][ni], 0, 0, 0);
            }
        __syncthreads();
    }

    // ---- vectorized epilogue through LDS (packed hi|lo uints) ----
    unsigned* Tp = (unsigned*)arena;                 // [64][132]
    const int n   = bm >> 11;
    const int wqb = bm & (WH - 1);
    const float qsc = (z == 0) ? 8.1611159f : 1.0f;  // sqrt(32)*log2(e) folded into Q

    #pragma unroll
    for (int p = 0; p < 2; p++) {
        if (wr == p) {
            #pragma unroll
            for (int mi = 0; mi < 4; mi++)
                #pragma unroll
                for (int ni = 0; ni < 4; ni++) {
                    const int lc = wc * 64 + ni * 16 + col;
                    const float bb = bias[bn + lc];
                    #pragma unroll
                    for (int r = 0; r < 4; r++) {
                        float v = (acc[mi][ni][r] + bb) * qsc;
                        unsigned short hb = bf16_rn(v);
                        unsigned short lb = bf16_rn(v - bf16_to_f(hb));
                        Tp[(mi * 16 + quad * 4 + r) * 132 + lc] =
                            (unsigned)hb | ((unsigned)lb << 16);
                    }
                }
        }
        __syncthreads();
        if (z == 2) {
            // transpose to Vt[(n*8+h)*32+d][wq], coalesced short8 stores
            const int c = tid >> 1, half = tid & 1;
            const int coln = bn + c, h = coln >> 5, d = coln & 31;
            unsigned short* dst =
                &Vt[((size_t)((n * NHD + h) * DH + d)) * WH + wqb + p * 64 + half * 32];
            unsigned hi[16];
            #pragma unroll
            for (int jj = 0; jj < 16; jj++) {
                unsigned u0 = Tp[(half * 32 + 2 * jj    ) * 132 + c];
                unsigned u1 = Tp[(half * 32 + 2 * jj + 1) * 132 + c];
                hi[jj] = __builtin_amdgcn_perm(u1, u0, 0x05040100);
            }
            #pragma unroll
            for (int s = 0; s < 4; s++)
                *(uint4*)&dst[s * 8] = make_uint4(hi[4*s], hi[4*s+1], hi[4*s+2], hi[4*s+3]);
        } else {
            // row-major hi/lo stores, 16B each
            const int lr = tid >> 2, seg = tid & 3;
            const int coln0 = bn + seg * 32, h = coln0 >> 5;
            const size_t off = ((size_t)((n * NHD + h) * WH) + wqb + p * 64 + lr) * DH;
            unsigned short* Thi = (z == 0) ? Qhi : Khi;
            unsigned short* Tlo = (z == 0) ? Qlo : Klo;
            #pragma unroll
            for (int s = 0; s < 4; s++) {
                unsigned u[8], hi[4], lo[4];
                *(uint4*)&u[0] = *(uint4*)&Tp[lr * 132 + seg * 32 + s * 8];
                *(uint4*)&u[4] = *(uint4*)&Tp[lr * 132 + seg * 32 + s * 8 + 4];
                #pragma unroll
                for (int jj = 0; jj < 4; jj++) {
                    hi[jj] = __builtin_amdgcn_perm(u[2*jj+1], u[2*jj], 0x05040100);
                    lo[jj] = __builtin_amdgcn_perm(u[2*jj+1], u[2*jj], 0x07060302);
                }
                *(uint4*)&Thi[off + s * 8] = make_uint4(hi[0], hi[1], hi[2], hi[3]);
                *(uint4*)&Tlo[off + s * 8] = make_uint4(lo[0], lo[1], lo[2], lo[3]);
            }
        }
        __syncthreads();
    }
}

// ---------------- transpose-free MFMA flash attention ----------------
// Wave w owns 16 q-rows. S^T = K·Q^T (C-layout: lane holds S[q=col][key=quad*4+r,
// 16+quad*4+r]) -> softmax entirely in-lane + 2 shfl. P^T (C-layout) is directly
// the B-fragment of mfma_16x16x16; O^T = V^T·P^T, rescale with lane-own alpha.
#define KSTR 40
__global__ __launch_bounds__(256) void attn(
    const unsigned short* __restrict__ Qhi, const unsigned short* __restrict__ Qlo,
    const unsigned short* __restrict__ Khi, const unsigned short* __restrict__ Klo,
    const unsigned short* __restrict__ Vt,  const float* __restrict__ X,
    float* __restrict__ Out)
{
    __shared__ __align__(16) unsigned short Ks [2][32 * KSTR];
    __shared__ __align__(16) unsigned short Kls[2][32 * KSTR];
    __shared__ __align__(16) unsigned short Vs [2][32 * KSTR];   // [d][key]

    const int tid  = threadIdx.x;
    const int w    = tid >> 6;
    const int lane = tid & 63;
    const int col  = lane & 15;
    const int quad = lane >> 4;
    const int nh   = blockIdx.y;
    const int q0   = blockIdx.x * 64;

    const size_t kbase = (size_t)nh * WH * DH;
    const size_t vbase = (size_t)nh * DH * WH;

    // Q fragments (pre-scaled by sqrt(32)*log2e); B-operand: n=col=qrow, k=quad*8+j
    const int qrow = q0 + w * 16 + col;
    const short8 qhi = *(const short8*)&Qhi[kbase + (size_t)qrow * DH + quad * 8];
    const short8 qlo = *(const short8*)&Qlo[kbase + (size_t)qrow * DH + quad * 8];

    // O^T accumulators: lane holds O[q=col][d=quad*4+r] (ot0), d+16 (ot1)
    f32x4 ot0 = {0.f, 0.f, 0.f, 0.f}, ot1 = {0.f, 0.f, 0.f, 0.f};
    float m_run = -INFINITY, l_run = 0.f;

    const int srow_ = tid >> 3;
    const int sc4   = (tid & 7) * 4;

    {   // preload tile 0
        *(uint2*)&Ks [0][srow_ * KSTR + sc4] = *(const uint2*)&Khi[kbase + (size_t)srow_ * DH + sc4];
        *(uint2*)&Kls[0][srow_ * KSTR + sc4] = *(const uint2*)&Klo[kbase + (size_t)srow_ * DH + sc4];
        *(uint2*)&Vs [0][srow_ * KSTR + sc4] = *(const uint2*)&Vt [vbase + (size_t)srow_ * WH + sc4];
    }
    __syncthreads();

    for (int kt = 0; kt < 64; kt++) {
        const int b = kt & 1;
        uint2 nk, nkl, nv;
        if (kt < 63) {
            const size_t ko = kbase + ((size_t)(kt + 1) * 32 + srow_) * DH + sc4;
            nk  = *(const uint2*)&Khi[ko];
            nkl = *(const uint2*)&Klo[ko];
            nv  = *(const uint2*)&Vt [vbase + (size_t)srow_ * WH + (kt + 1) * 32 + sc4];
        }

        // K fragments as A-operand: m=col(+16)=key, k=quad*8+j=d
        const short8 kh0 = *(const short8*)&Ks [b][(col     ) * KSTR + quad * 8];
        const short8 kh1 = *(const short8*)&Ks [b][(col + 16) * KSTR + quad * 8];
        const short8 kl0 = *(const short8*)&Kls[b][(col     ) * KSTR + quad * 8];
        const short8 kl1 = *(const short8*)&Kls[b][(col + 16) * KSTR + quad * 8];

        // S^T = K·Q^T  (Khi·Qlo + Klo·Qhi + Khi·Qhi)
        f32x4 s0 = {0.f, 0.f, 0.f, 0.f}, s1 = {0.f, 0.f, 0.f, 0.f};
        s0 = __builtin_amdgcn_mfma_f32_16x16x32_bf16(kh0, qlo, s0, 0, 0, 0);
        s0 = __builtin_amdgcn_mfma_f32_16x16x32_bf16(kl0, qhi, s0, 0, 0, 0);
        s0 = __builtin_amdgcn_mfma_f32_16x16x32_bf16(kh0, qhi, s0, 0, 0, 0);
        s1 = __builtin_amdgcn_mfma_f32_16x16x32_bf16(kh1, qlo, s1, 0, 0, 0);
        s1 = __builtin_amdgcn_mfma_f32_16x16x32_bf16(kl1, qhi, s1, 0, 0, 0);
        s1 = __builtin_amdgcn_mfma_f32_16x16x32_bf16(kh1, qhi, s1, 0, 0, 0);

        // online softmax in log2 domain (scale pre-folded into Q)
        float mx = fmaxf(fmaxf(fmaxf(s0[0], s0[1]), fmaxf(s0[2], s0[3])),
                         fmaxf(fmaxf(s1[0], s1[1]), fmaxf(s1[2], s1[3])));
        mx = fmaxf(mx, __shfl_xor(mx, 16));
        mx = fmaxf(mx, __shfl_xor(mx, 32));
        const float mnew  = fmaxf(m_run, mx);
        const float alpha = exp2f(m_run - mnew);

        float p0[4], p1[4], ps = 0.f;
        #pragma unroll
        for (int r = 0; r < 4; r++) {
            p0[r] = exp2f(s0[r] - mnew); ps += p0[r];
            p1[r] = exp2f(s1[r] - mnew); ps += p1[r];
        }
        ps += __shfl_xor(ps, 16);
        ps += __shfl_xor(ps, 32);
        l_run = l_run * alpha + ps;
        m_run = mnew;

        // P^T in C-layout IS the 16x16x16 B-fragment: B[k=quad*4+j=key][n=col=qrow]
        short4v pb0, pb1;
        #pragma unroll
        for (int r = 0; r < 4; r++) {
            pb0[r] = (short)bf16_rn(p0[r]);
            pb1[r] = (short)bf16_rn(p1[r]);
        }

        // rescale O^T with lane-own alpha
        #pragma unroll
        for (int r = 0; r < 4; r++) { ot0[r] *= alpha; ot1[r] *= alpha; }

        // V^T fragments as A-operand of 16x16x16: m=col(+16)=d, k=quad*4+j=key
        const short4v va00 = *(const short4v*)&Vs[b][(col     ) * KSTR + quad * 4];
        const short4v va01 = *(const short4v*)&Vs[b][(col     ) * KSTR + 16 + quad * 4];
        const short4v va10 = *(const short4v*)&Vs[b][(col + 16) * KSTR + quad * 4];
        const short4v va11 = *(const short4v*)&Vs[b][(col + 16) * KSTR + 16 + quad * 4];

        ot0 = __builtin_amdgcn_mfma_f32_16x16x16bf16_1k(va00, pb0, ot0, 0, 0, 0);
        ot0 = __builtin_amdgcn_mfma_f32_16x16x16bf16_1k(va01, pb1, ot0, 0, 0, 0);
        ot1 = __builtin_amdgcn_mfma_f32_16x16x16bf16_1k(va10, pb0, ot1, 0, 0, 0);
        ot1 = __builtin_amdgcn_mfma_f32_16x16x16bf16_1k(va11, pb1, ot1, 0, 0, 0);

        if (kt < 63) {
            *(uint2*)&Ks [b ^ 1][srow_ * KSTR + sc4] = nk;
            *(uint2*)&Kls[b ^ 1][srow_ * KSTR + sc4] = nkl;
            *(uint2*)&Vs [b ^ 1][srow_ * KSTR + sc4] = nv;
        }
        __syncthreads();
    }

    // epilogue: lane owns row q=col, d = quad*4..+3 and +16 -> float4 stores
    const float inv = 1.f / l_run;
    const int n = nh >> 3, h = nh & 7;
    const size_t a0 = ((size_t)n * WH + qrow) * DM + h * DH + quad * 4;
    float4 x0 = *(const float4*)&X[a0];
    float4 y0;
    y0.x = ot0[0] * inv + x0.x;
    y0.y = ot0[1] * inv + x0.y;
    y0.z = ot0[2] * inv + x0.z;
    y0.w = ot0[3] * inv + x0.w;
    *(float4*)&Out[a0] = y0;
    float4 x1 = *(const float4*)&X[a0 + 16];
    float4 y1;
    y1.x = ot1[0] * inv + x1.x;
    y1.y = ot1[1] * inv + x1.y;
    y1.z = ot1[2] * inv + x1.z;
    y1.w = ot1[3] * inv + x1.w;
    *(float4*)&Out[a0 + 16] = y1;
}

extern "C" void kernel_launch(void* const* d_in, const int* in_sizes, int n_in,
                              void* d_out, int out_size, void* d_ws, size_t ws_size,
                              hipStream_t stream) {
    const float* x  = (const float*)d_in[0];
    const float* Wq = (const float*)d_in[1];
    const float* bq = (const float*)d_in[2];
    const float* Wk = (const float*)d_in[3];
    const float* bk = (const float*)d_in[4];
    const float* Wv = (const float*)d_in[5];
    const float* bv = (const float*)d_in[6];
    float* out = (float*)d_out;

    const size_t elems = (size_t)NB * WH * DM;
    unsigned short* Qhi  = (unsigned short*)d_ws;
    unsigned short* Qlo  = Qhi + elems;
    unsigned short* Khi  = Qlo + elems;
    unsigned short* Klo  = Khi + elems;
    unsigned short* Vt   = Klo + elems;
    unsigned short* WThi = Vt  + elems;
    unsigned short* WTlo = WThi + (size_t)3 * DM * DM;

    dim3 gw(16, 3);
    wprep<<<gw, 256, 0, stream>>>(Wq, Wk, Wv, WThi, WTlo);

    dim3 gg(128, 2, 3);
    qkv_mfma<<<gg, 256, 0, stream>>>(x, WThi, WTlo, bq, bk, bv,
                                     Qhi, Qlo, Khi, Klo, Vt);

    dim3 ga(WH / 64, NB * NHD);
    attn<<<ga, 256, 0, stream>>>(Qhi, Qlo, Khi, Klo, Vt, x, out);
}

// Round 6
// 247.919 us; speedup vs baseline: 4.0830x; 1.0985x over previous
//
#include <hip/hip_runtime.h>
#include <math.h>

// MHSA round 6: async global_load_lds staging, raw v_exp_f32, 2 q-frags/wave,
// X pre-split once (scratch = d_out). V stored attn-tile-major [nh][kt][d][key32].
#define WH 2048
#define DM 256
#define NHD 8
#define DH 32
#define NB 8

typedef __attribute__((ext_vector_type(8))) short short8;
typedef __attribute__((ext_vector_type(4))) short short4v;
typedef __attribute__((ext_vector_type(4))) float f32x4;

__device__ __forceinline__ unsigned short bf16_rn(float f) {
    unsigned u = __float_as_uint(f);
    return (unsigned short)((u + 0x8000u) >> 16);
}
__device__ __forceinline__ float bf16_to_f(unsigned short h) {
    return __uint_as_float(((unsigned)h) << 16);
}
// pack two fp32 -> [bf16(f0) | bf16(f1)<<16], round-to-nearest
__device__ __forceinline__ unsigned pack_bf16_rn(float f1, float f0) {
    return __builtin_amdgcn_perm(__float_as_uint(f1) + 0x8000u,
                                 __float_as_uint(f0) + 0x8000u, 0x07060302);
}
// async 16B/lane global->LDS (lds dst = uniform base + lane*16)
__device__ __forceinline__ void glds16(const void* g, void* l) {
    __builtin_amdgcn_global_load_lds(
        (const __attribute__((address_space(1))) unsigned int*)g,
        (__attribute__((address_space(3))) unsigned int*)l, 16, 0, 0);
}

// ---------------- X prep: fp32 -> bf16 hi/lo split, once ----------------
__global__ __launch_bounds__(256) void xprep(
    const float* __restrict__ X,
    unsigned short* __restrict__ Xhi, unsigned short* __restrict__ Xlo)
{
    const size_t i = ((size_t)blockIdx.x * 256 + threadIdx.x) * 8;
    float4 a = *(const float4*)&X[i];
    float4 b = *(const float4*)&X[i + 4];
    float v[8] = {a.x, a.y, a.z, a.w, b.x, b.y, b.z, b.w};
    short8 hi, lo;
    #pragma unroll
    for (int e = 0; e < 8; e++) {
        unsigned short hb = bf16_rn(v[e]);
        hi[e] = (short)hb;
        lo[e] = (short)bf16_rn(v[e] - bf16_to_f(hb));
    }
    *(short8*)&Xhi[i] = hi;
    *(short8*)&Xlo[i] = lo;
}

// ---------------- W prep: transpose + split to bf16 hi/lo ----------------
__global__ __launch_bounds__(256) void wprep(
    const float* __restrict__ Wq, const float* __restrict__ Wk,
    const float* __restrict__ Wv,
    unsigned short* __restrict__ WThi, unsigned short* __restrict__ WTlo)
{
    const int z = blockIdx.y;
    const float* W = (z == 0) ? Wq : ((z == 1) ? Wk : Wv);
    const size_t zoff = (size_t)z * DM * DM;
    const int tg = blockIdx.x * 256 + threadIdx.x;
    #pragma unroll
    for (int j = 0; j < 4; j++) {
        const int f = tg + j * 4096;
        const int k  = f >> 6;
        const int n0 = (f & 63) * 4;
        float4 v = *(const float4*)&W[(size_t)k * DM + n0];
        float vv[4] = {v.x, v.y, v.z, v.w};
        #pragma unroll
        for (int i = 0; i < 4; i++) {
            unsigned short hb = bf16_rn(vv[i]);
            WThi[zoff + (size_t)(n0 + i) * DM + k] = hb;
            WTlo[zoff + (size_t)(n0 + i) * DM + k] = bf16_rn(vv[i] - bf16_to_f(hb));
        }
    }
}

// ---------------- QKV projection: split-bf16 MFMA GEMM ----------------
#define ASTR 40
__global__ __launch_bounds__(256) void qkv_mfma(
    const unsigned short* __restrict__ Xhi, const unsigned short* __restrict__ Xlo,
    const unsigned short* __restrict__ WThi, const unsigned short* __restrict__ WTlo,
    const float* __restrict__ bq, const float* __restrict__ bk, const float* __restrict__ bv,
    unsigned short* __restrict__ Qhi, unsigned short* __restrict__ Qlo,
    unsigned short* __restrict__ Khi, unsigned short* __restrict__ Klo,
    unsigned short* __restrict__ Vt)
{
    __shared__ __align__(16) char arena[40960];
    unsigned short* Ah = (unsigned short*)arena;
    unsigned short* Al = Ah + 128 * ASTR;
    unsigned short* Bh = Al + 128 * ASTR;
    unsigned short* Bl = Bh + 128 * ASTR;

    const int z = blockIdx.z;
    const float* bias = (z == 0) ? bq : ((z == 1) ? bk : bv);
    const size_t zoff = (size_t)z * DM * DM;

    const int tid  = threadIdx.x;
    const int w    = tid >> 6;
    const int lane = tid & 63;
    const int col  = lane & 15;
    const int quad = lane >> 4;
    const int wr = w >> 1, wc = w & 1;
    const int bm = blockIdx.x * 128;
    const int bn = blockIdx.y * 128;

    f32x4 acc[4][4];
    #pragma unroll
    for (int mi = 0; mi < 4; mi++)
        #pragma unroll
        for (int ni = 0; ni < 4; ni++) acc[mi][ni] = (f32x4){0.f, 0.f, 0.f, 0.f};

    for (int kb = 0; kb < 8; kb++) {
        const int k0 = kb * 32;
        // stage A and B tiles: pure bf16 16B copies
        #pragma unroll
        for (int i = 0; i < 2; i++) {
            const int idx = tid + 256 * i;
            const int r  = idx >> 2;
            const int c8 = (idx & 3) * 8;
            *(uint4*)&Ah[r * ASTR + c8] = *(const uint4*)&Xhi[(size_t)(bm + r) * DM + k0 + c8];
            *(uint4*)&Al[r * ASTR + c8] = *(const uint4*)&Xlo[(size_t)(bm + r) * DM + k0 + c8];
            *(uint4*)&Bh[r * ASTR + c8] = *(const uint4*)&WThi[zoff + (size_t)(bn + r) * DM + k0 + c8];
            *(uint4*)&Bl[r * ASTR + c8] = *(const uint4*)&WTlo[zoff + (size_t)(bn + r) * DM + k0 + c8];
        }
        __syncthreads();

        short8 ah[4], al[4], bh[4], bl[4];
        #pragma unroll
        for (int mi = 0; mi < 4; mi++) {
            const int row = wr * 64 + mi * 16 + col;
            ah[mi] = *(const short8*)&Ah[row * ASTR + quad * 8];
            al[mi] = *(const short8*)&Al[row * ASTR + quad * 8];
        }
        #pragma unroll
        for (int ni = 0; ni < 4; ni++) {
            const int nn = wc * 64 + ni * 16 + col;
            bh[ni] = *(const short8*)&Bh[nn * ASTR + quad * 8];
            bl[ni] = *(const short8*)&Bl[nn * ASTR + quad * 8];
        }
        #pragma unroll
        for (int mi = 0; mi < 4; mi++)
            #pragma unroll
            for (int ni = 0; ni < 4; ni++) {
                acc[mi][ni] = __builtin_amdgcn_mfma_f32_16x16x32_bf16(al[mi], bh[ni], acc[mi][ni], 0, 0, 0);
                acc[mi][ni] = __builtin_amdgcn_mfma_f32_16x16x32_bf16(ah[mi], bl[ni], acc[mi][ni], 0, 0, 0);
                acc[mi][ni] = __builtin_amdgcn_mfma_f32_16x16x32_bf16(ah[mi], bh[ni], acc[mi][ni], 0, 0, 0);
            }
        __syncthreads();
    }

    // ---- vectorized epilogue through LDS (packed hi|lo uints) ----
    unsigned* Tp = (unsigned*)arena;                 // [64][132]
    const int n   = bm >> 11;
    const int wqb = bm & (WH - 1);
    const float qsc = (z == 0) ? 8.1611159f : 1.0f;  // sqrt(32)*log2(e) folded into Q

    #pragma unroll
    for (int p = 0; p < 2; p++) {
        if (wr == p) {
            #pragma unroll
            for (int mi = 0; mi < 4; mi++)
                #pragma unroll
                for (int ni = 0; ni < 4; ni++) {
                    const int lc = wc * 64 + ni * 16 + col;
                    const float bb = bias[bn + lc];
                    #pragma unroll
                    for (int r = 0; r < 4; r++) {
                        float v = (acc[mi][ni][r] + bb) * qsc;
                        unsigned short hb = bf16_rn(v);
                        unsigned short lb = bf16_rn(v - bf16_to_f(hb));
                        Tp[(mi * 16 + quad * 4 + r) * 132 + lc] =
                            (unsigned)hb | ((unsigned)lb << 16);
                    }
                }
        }
        __syncthreads();
        if (z == 2) {
            // V in attn-tile layout: Vt[((nh*64 + tI)*32 + d)*32 + key']
            const int c = tid >> 1, half = tid & 1;
            const int coln = bn + c, h = coln >> 5, d = coln & 31;
            const int tI = (wqb + p * 64 + half * 32) >> 5;
            unsigned short* dst =
                &Vt[(((size_t)(n * NHD + h) * 64 + tI) * 32 + d) * 32];
            unsigned hi[16];
            #pragma unroll
            for (int jj = 0; jj < 16; jj++) {
                unsigned u0 = Tp[(half * 32 + 2 * jj    ) * 132 + c];
                unsigned u1 = Tp[(half * 32 + 2 * jj + 1) * 132 + c];
                hi[jj] = __builtin_amdgcn_perm(u1, u0, 0x05040100);
            }
            #pragma unroll
            for (int s = 0; s < 4; s++)
                *(uint4*)&dst[s * 8] = make_uint4(hi[4*s], hi[4*s+1], hi[4*s+2], hi[4*s+3]);
        } else {
            const int lr = tid >> 2, seg = tid & 3;
            const int coln0 = bn + seg * 32, h = coln0 >> 5;
            const size_t off = ((size_t)((n * NHD + h) * WH) + wqb + p * 64 + lr) * DH;
            unsigned short* Thi = (z == 0) ? Qhi : Khi;
            unsigned short* Tlo = (z == 0) ? Qlo : Klo;
            #pragma unroll
            for (int s = 0; s < 4; s++) {
                unsigned u[8], hi[4], lo[4];
                *(uint4*)&u[0] = *(uint4*)&Tp[lr * 132 + seg * 32 + s * 8];
                *(uint4*)&u[4] = *(uint4*)&Tp[lr * 132 + seg * 32 + s * 8 + 4];
                #pragma unroll
                for (int jj = 0; jj < 4; jj++) {
                    hi[jj] = __builtin_amdgcn_perm(u[2*jj+1], u[2*jj], 0x05040100);
                    lo[jj] = __builtin_amdgcn_perm(u[2*jj+1], u[2*jj], 0x07060302);
                }
                *(uint4*)&Thi[off + s * 8] = make_uint4(hi[0], hi[1], hi[2], hi[3]);
                *(uint4*)&Tlo[off + s * 8] = make_uint4(lo[0], lo[1], lo[2], lo[3]);
            }
        }
        __syncthreads();
    }
}

// ---------------- MFMA flash attention ----------------
// 256 thr = 4 waves; wave w owns 2 q-fragments (rows q0+f*64+w*16+col).
// K/V tiles (2KB each, globally contiguous) staged via global_load_lds:
// wave0->Khi, wave1->Klo, wave2/3 -> V halves. Static unroll-2 double buffer.
__global__ __launch_bounds__(256, 4) void attn(
    const unsigned short* __restrict__ Qhi, const unsigned short* __restrict__ Qlo,
    const unsigned short* __restrict__ Khi, const unsigned short* __restrict__ Klo,
    const unsigned short* __restrict__ Vt,  const float* __restrict__ X,
    float* __restrict__ Out)
{
    __shared__ __align__(16) unsigned short Kh[2][1024];
    __shared__ __align__(16) unsigned short Kl[2][1024];
    __shared__ __align__(16) unsigned short Vv[2][1024];   // per tile: [d][key32]

    const int tid  = threadIdx.x;
    const int w    = tid >> 6;
    const int lane = tid & 63;
    const int col  = lane & 15;
    const int quad = lane >> 4;
    const int nh   = blockIdx.y;
    const int q0   = blockIdx.x * 128;
    const size_t base = (size_t)nh * WH * DH;   // 65536 elements per head, K and Vt alike

    short8 qh[2], ql[2];
    #pragma unroll
    for (int f = 0; f < 2; f++) {
        const int qrow = q0 + f * 64 + w * 16 + col;
        qh[f] = *(const short8*)&Qhi[base + (size_t)qrow * DH + quad * 8];
        ql[f] = *(const short8*)&Qlo[base + (size_t)qrow * DH + quad * 8];
    }

    f32x4 ot00 = {0.f,0.f,0.f,0.f}, ot01 = {0.f,0.f,0.f,0.f};
    f32x4 ot10 = {0.f,0.f,0.f,0.f}, ot11 = {0.f,0.f,0.f,0.f};
    float mr0 = -INFINITY, mr1 = -INFINITY, lr0 = 0.f, lr1 = 0.f;

    // staging assignment
    const char* gb;
    unsigned short *ld0, *ld1;
    if (w == 0)      { gb = (const char*)(Khi + base);        ld0 = &Kh[0][0];   ld1 = &Kh[1][0];   }
    else if (w == 1) { gb = (const char*)(Klo + base);        ld0 = &Kl[0][0];   ld1 = &Kl[1][0];   }
    else if (w == 2) { gb = (const char*)(Vt  + base);        ld0 = &Vv[0][0];   ld1 = &Vv[1][0];   }
    else             { gb = (const char*)(Vt  + base) + 1024; ld0 = &Vv[0][512]; ld1 = &Vv[1][512]; }
    gb += (size_t)lane * 16;

    auto issue = [&](int t, unsigned short* ld) {
        const char* g = gb + (size_t)t * 2048;
        glds16(g, ld);
        if (w < 2) glds16(g + 1024, ld + 512);
    };

    auto body = [&](int b) {
        const short8 kh0 = *(const short8*)&Kh[b][(col     ) * 32 + quad * 8];
        const short8 kh1 = *(const short8*)&Kh[b][(col + 16) * 32 + quad * 8];
        const short8 kl0 = *(const short8*)&Kl[b][(col     ) * 32 + quad * 8];
        const short8 kl1 = *(const short8*)&Kl[b][(col + 16) * 32 + quad * 8];
        const short4v va00 = *(const short4v*)&Vv[b][(col     ) * 32 + quad * 4];
        const short4v va01 = *(const short4v*)&Vv[b][(col     ) * 32 + 16 + quad * 4];
        const short4v va10 = *(const short4v*)&Vv[b][(col + 16) * 32 + quad * 4];
        const short4v va11 = *(const short4v*)&Vv[b][(col + 16) * 32 + 16 + quad * 4];

        #pragma unroll
        for (int f = 0; f < 2; f++) {
            f32x4 s0 = {0.f,0.f,0.f,0.f}, s1 = {0.f,0.f,0.f,0.f};
            s0 = __builtin_amdgcn_mfma_f32_16x16x32_bf16(kh0, ql[f], s0, 0, 0, 0);
            s0 = __builtin_amdgcn_mfma_f32_16x16x32_bf16(kl0, qh[f], s0, 0, 0, 0);
            s0 = __builtin_amdgcn_mfma_f32_16x16x32_bf16(kh0, qh[f], s0, 0, 0, 0);
            s1 = __builtin_amdgcn_mfma_f32_16x16x32_bf16(kh1, ql[f], s1, 0, 0, 0);
            s1 = __builtin_amdgcn_mfma_f32_16x16x32_bf16(kl1, qh[f], s1, 0, 0, 0);
            s1 = __builtin_amdgcn_mfma_f32_16x16x32_bf16(kh1, qh[f], s1, 0, 0, 0);

            float mx = fmaxf(fmaxf(fmaxf(s0[0], s0[1]), fmaxf(s0[2], s0[3])),
                             fmaxf(fmaxf(s1[0], s1[1]), fmaxf(s1[2], s1[3])));
            mx = fmaxf(mx, __shfl_xor(mx, 16));
            mx = fmaxf(mx, __shfl_xor(mx, 32));
            float& mrf = f ? mr1 : mr0;
            float& lrf = f ? lr1 : lr0;
            const float mnew  = fmaxf(mrf, mx);
            const float alpha = __builtin_amdgcn_exp2f(mrf - mnew);

            float p0[4], p1[4], ps = 0.f;
            #pragma unroll
            for (int r = 0; r < 4; r++) {
                p0[r] = __builtin_amdgcn_exp2f(s0[r] - mnew); ps += p0[r];
                p1[r] = __builtin_amdgcn_exp2f(s1[r] - mnew); ps += p1[r];
            }
            ps += __shfl_xor(ps, 16);
            ps += __shfl_xor(ps, 32);
            lrf = lrf * alpha + ps;
            mrf = mnew;

            union { short4v v; unsigned u[2]; } Pb0, Pb1;
            Pb0.u[0] = pack_bf16_rn(p0[1], p0[0]);
            Pb0.u[1] = pack_bf16_rn(p0[3], p0[2]);
            Pb1.u[0] = pack_bf16_rn(p1[1], p1[0]);
            Pb1.u[1] = pack_bf16_rn(p1[3], p1[2]);

            f32x4& o0 = f ? ot10 : ot00;
            f32x4& o1 = f ? ot11 : ot01;
            #pragma unroll
            for (int r = 0; r < 4; r++) { o0[r] *= alpha; o1[r] *= alpha; }
            o0 = __builtin_amdgcn_mfma_f32_16x16x16bf16_1k(va00, Pb0.v, o0, 0, 0, 0);
            o0 = __builtin_amdgcn_mfma_f32_16x16x16bf16_1k(va01, Pb1.v, o0, 0, 0, 0);
            o1 = __builtin_amdgcn_mfma_f32_16x16x16bf16_1k(va10, Pb0.v, o1, 0, 0, 0);
            o1 = __builtin_amdgcn_mfma_f32_16x16x16bf16_1k(va11, Pb1.v, o1, 0, 0, 0);
        }
    };

    issue(0, ld0);
    __syncthreads();
    for (int kt2 = 0; kt2 < 32; kt2++) {
        issue(2 * kt2 + 1, ld1);
        body(0);
        __syncthreads();
        if (kt2 < 31) issue(2 * kt2 + 2, ld0);
        body(1);
        __syncthreads();
    }

    // epilogue
    const int n = nh >> 3, h = nh & 7;
    #pragma unroll
    for (int f = 0; f < 2; f++) {
        const float inv = 1.f / (f ? lr1 : lr0);
        const f32x4& o0 = f ? ot10 : ot00;
        const f32x4& o1 = f ? ot11 : ot01;
        const int qrow = q0 + f * 64 + w * 16 + col;
        const size_t a0 = ((size_t)n * WH + qrow) * DM + h * DH + quad * 4;
        float4 x0 = *(const float4*)&X[a0];
        float4 y0;
        y0.x = o0[0] * inv + x0.x;
        y0.y = o0[1] * inv + x0.y;
        y0.z = o0[2] * inv + x0.z;
        y0.w = o0[3] * inv + x0.w;
        *(float4*)&Out[a0] = y0;
        float4 x1 = *(const float4*)&X[a0 + 16];
        float4 y1;
        y1.x = o1[0] * inv + x1.x;
        y1.y = o1[1] * inv + x1.y;
        y1.z = o1[2] * inv + x1.z;
        y1.w = o1[3] * inv + x1.w;
        *(float4*)&Out[a0 + 16] = y1;
    }
}

extern "C" void kernel_launch(void* const* d_in, const int* in_sizes, int n_in,
                              void* d_out, int out_size, void* d_ws, size_t ws_size,
                              hipStream_t stream) {
    const float* x  = (const float*)d_in[0];
    const float* Wq = (const float*)d_in[1];
    const float* bq = (const float*)d_in[2];
    const float* Wk = (const float*)d_in[3];
    const float* bk = (const float*)d_in[4];
    const float* Wv = (const float*)d_in[5];
    const float* bv = (const float*)d_in[6];
    float* out = (float*)d_out;

    const size_t elems = (size_t)NB * WH * DM;   // 4,194,304
    unsigned short* Qhi  = (unsigned short*)d_ws;
    unsigned short* Qlo  = Qhi + elems;
    unsigned short* Khi  = Qlo + elems;
    unsigned short* Klo  = Khi + elems;
    unsigned short* Vt   = Klo + elems;
    unsigned short* WThi = Vt  + elems;
    unsigned short* WTlo = WThi + (size_t)3 * DM * DM;

    // X hi/lo split lives in d_out (16.78 MB, exactly out bytes); attn fully
    // overwrites d_out afterwards.
    unsigned short* Xhi = (unsigned short*)d_out;
    unsigned short* Xlo = Xhi + elems;

    xprep<<<2048, 256, 0, stream>>>(x, Xhi, Xlo);

    dim3 gw(16, 3);
    wprep<<<gw, 256, 0, stream>>>(Wq, Wk, Wv, WThi, WTlo);

    dim3 gg(128, 2, 3);
    qkv_mfma<<<gg, 256, 0, stream>>>(Xhi, Xlo, WThi, WTlo, bq, bk, bv,
                                     Qhi, Qlo, Khi, Klo, Vt);

    dim3 ga(WH / 128, NB * NHD);   // (16, 64) = 1024 blocks
    attn<<<ga, 256, 0, stream>>>(Qhi, Qlo, Khi, Klo, Vt, x, out);
}

// Round 7
// 232.633 us; speedup vs baseline: 4.3513x; 1.0657x over previous
//
#include <hip/hip_runtime.h>
#include <math.h>

// MHSA round 7: XOR-swizzled DMA gather (conflict-free LDS fragment reads)
// for both attn and qkv; qkv K-loop double-buffered via global_load_lds.
#define WH 2048
#define DM 256
#define NHD 8
#define DH 32
#define NB 8

typedef __attribute__((ext_vector_type(8))) short short8;
typedef __attribute__((ext_vector_type(4))) short short4v;
typedef __attribute__((ext_vector_type(4))) float f32x4;

__device__ __forceinline__ unsigned short bf16_rn(float f) {
    unsigned u = __float_as_uint(f);
    return (unsigned short)((u + 0x8000u) >> 16);
}
__device__ __forceinline__ float bf16_to_f(unsigned short h) {
    return __uint_as_float(((unsigned)h) << 16);
}
__device__ __forceinline__ unsigned pack_bf16_rn(float f1, float f0) {
    return __builtin_amdgcn_perm(__float_as_uint(f1) + 0x8000u,
                                 __float_as_uint(f0) + 0x8000u, 0x07060302);
}
__device__ __forceinline__ void glds16(const void* g, void* l) {
    __builtin_amdgcn_global_load_lds(
        (const __attribute__((address_space(1))) unsigned int*)g,
        (__attribute__((address_space(3))) unsigned int*)l, 16, 0, 0);
}

// ---------------- X prep: fp32 -> bf16 hi/lo split, once ----------------
__global__ __launch_bounds__(256) void xprep(
    const float* __restrict__ X,
    unsigned short* __restrict__ Xhi, unsigned short* __restrict__ Xlo)
{
    const size_t i = ((size_t)blockIdx.x * 256 + threadIdx.x) * 8;
    float4 a = *(const float4*)&X[i];
    float4 b = *(const float4*)&X[i + 4];
    float v[8] = {a.x, a.y, a.z, a.w, b.x, b.y, b.z, b.w};
    short8 hi, lo;
    #pragma unroll
    for (int e = 0; e < 8; e++) {
        unsigned short hb = bf16_rn(v[e]);
        hi[e] = (short)hb;
        lo[e] = (short)bf16_rn(v[e] - bf16_to_f(hb));
    }
    *(short8*)&Xhi[i] = hi;
    *(short8*)&Xlo[i] = lo;
}

// ---------------- W prep: transpose + split to bf16 hi/lo ----------------
__global__ __launch_bounds__(256) void wprep(
    const float* __restrict__ Wq, const float* __restrict__ Wk,
    const float* __restrict__ Wv,
    unsigned short* __restrict__ WThi, unsigned short* __restrict__ WTlo)
{
    const int z = blockIdx.y;
    const float* W = (z == 0) ? Wq : ((z == 1) ? Wk : Wv);
    const size_t zoff = (size_t)z * DM * DM;
    const int tg = blockIdx.x * 256 + threadIdx.x;
    #pragma unroll
    for (int j = 0; j < 4; j++) {
        const int f = tg + j * 4096;
        const int k  = f >> 6;
        const int n0 = (f & 63) * 4;
        float4 v = *(const float4*)&W[(size_t)k * DM + n0];
        float vv[4] = {v.x, v.y, v.z, v.w};
        #pragma unroll
        for (int i = 0; i < 4; i++) {
            unsigned short hb = bf16_rn(vv[i]);
            WThi[zoff + (size_t)(n0 + i) * DM + k] = hb;
            WTlo[zoff + (size_t)(n0 + i) * DM + k] = bf16_rn(vv[i] - bf16_to_f(hb));
        }
    }
}

// ---------------- QKV projection: split-bf16 MFMA, swizzled DMA dbuf ----------------
// Block 256 thr = 4 waves; tile 128x128, BK=32, 8 K-iters.
// Wave w DMA-stages array w (Ah/Al/Bh/Bl), 8KB each, XOR-swizzled gather so
// fragment b128 reads are bank-conflict-free. Double-buffered (64KB LDS).
__global__ __launch_bounds__(256, 1) void qkv_mfma(
    const unsigned short* __restrict__ Xhi, const unsigned short* __restrict__ Xlo,
    const unsigned short* __restrict__ WThi, const unsigned short* __restrict__ WTlo,
    const float* __restrict__ bq, const float* __restrict__ bk, const float* __restrict__ bv,
    unsigned short* __restrict__ Qhi, unsigned short* __restrict__ Qlo,
    unsigned short* __restrict__ Khi, unsigned short* __restrict__ Klo,
    unsigned short* __restrict__ Vt)
{
    // arena: 4 arrays x 2 buffers x 4096 shorts = 64 KB; epilogue reuses it.
    __shared__ __align__(16) unsigned short arena[4 * 2 * 4096];

    const int z = blockIdx.z;
    const float* bias = (z == 0) ? bq : ((z == 1) ? bk : bv);
    const size_t zoff = (size_t)z * DM * DM;

    const int tid  = threadIdx.x;
    const int w    = tid >> 6;
    const int lane = tid & 63;
    const int col  = lane & 15;
    const int quad = lane >> 4;
    const int wr = w >> 1, wc = w & 1;
    const int bm = blockIdx.x * 128;
    const int bn = blockIdx.y * 128;

    // swizzled per-lane gather: lane L -> physical chunk L; reads logical
    // chunk (r = L>>2, c = (L&3) ^ ((L>>3)&3)) of the 16-row segment.
    const int perm16 = (((lane & 3) ^ ((lane >> 3) & 3))) * 16;
    const char* glane;
    if (w == 0)      glane = (const char*)Xhi + (size_t)(bm + (lane >> 2)) * 512 + perm16;
    else if (w == 1) glane = (const char*)Xlo + (size_t)(bm + (lane >> 2)) * 512 + perm16;
    else if (w == 2) glane = (const char*)(WThi + zoff) + (size_t)(bn + (lane >> 2)) * 512 + perm16;
    else             glane = (const char*)(WTlo + zoff) + (size_t)(bn + (lane >> 2)) * 512 + perm16;

    auto issue = [&](int kb, int b) {
        const char* g0 = glane + (size_t)kb * 64;   // k0*2 bytes
        unsigned short* l0 = &arena[w * 8192 + b * 4096];
        #pragma unroll
        for (int g = 0; g < 8; g++)
            glds16(g0 + (size_t)g * 8192, l0 + g * 512);   // g*16 rows
    };

    f32x4 acc[4][4];
    #pragma unroll
    for (int mi = 0; mi < 4; mi++)
        #pragma unroll
        for (int ni = 0; ni < 4; ni++) acc[mi][ni] = (f32x4){0.f, 0.f, 0.f, 0.f};

    // swizzled fragment offset: row*32 + (quad ^ ((col>>1)&3))*8
    const int sw = (col >> 1) & 3;
    const int fO = (quad ^ sw) * 8;

    issue(0, 0);
    __syncthreads();
    for (int kb = 0; kb < 8; kb++) {
        const int b = kb & 1;
        if (kb < 7) issue(kb + 1, b ^ 1);

        short8 ah[4], al[4], bh[4], bl[4];
        #pragma unroll
        for (int mi = 0; mi < 4; mi++) {
            const int ro = (wr * 64 + mi * 16 + col) * 32 + fO;
            ah[mi] = *(const short8*)&arena[        b * 4096 + ro];
            al[mi] = *(const short8*)&arena[ 8192 + b * 4096 + ro];
        }
        #pragma unroll
        for (int ni = 0; ni < 4; ni++) {
            const int no = (wc * 64 + ni * 16 + col) * 32 + fO;
            bh[ni] = *(const short8*)&arena[16384 + b * 4096 + no];
            bl[ni] = *(const short8*)&arena[24576 + b * 4096 + no];
        }
        #pragma unroll
        for (int mi = 0; mi < 4; mi++)
            #pragma unroll
            for (int ni = 0; ni < 4; ni++) {
                acc[mi][ni] = __builtin_amdgcn_mfma_f32_16x16x32_bf16(al[mi], bh[ni], acc[mi][ni], 0, 0, 0);
                acc[mi][ni] = __builtin_amdgcn_mfma_f32_16x16x32_bf16(ah[mi], bl[ni], acc[mi][ni], 0, 0, 0);
                acc[mi][ni] = __builtin_amdgcn_mfma_f32_16x16x32_bf16(ah[mi], bh[ni], acc[mi][ni], 0, 0, 0);
            }
        __syncthreads();
    }

    // ---- vectorized epilogue through LDS (packed hi|lo uints) ----
    unsigned* Tp = (unsigned*)arena;                 // [64][132] = 33.8 KB
    const int n   = bm >> 11;
    const int wqb = bm & (WH - 1);
    const float qsc = (z == 0) ? 8.1611159f : 1.0f;  // sqrt(32)*log2(e) folded into Q

    #pragma unroll
    for (int p = 0; p < 2; p++) {
        if (wr == p) {
            #pragma unroll
            for (int mi = 0; mi < 4; mi++)
                #pragma unroll
                for (int ni = 0; ni < 4; ni++) {
                    const int lc = wc * 64 + ni * 16 + col;
                    const float bb = bias[bn + lc];
                    #pragma unroll
                    for (int r = 0; r < 4; r++) {
                        float v = (acc[mi][ni][r] + bb) * qsc;
                        unsigned short hb = bf16_rn(v);
                        unsigned short lb = bf16_rn(v - bf16_to_f(hb));
                        Tp[(mi * 16 + quad * 4 + r) * 132 + lc] =
                            (unsigned)hb | ((unsigned)lb << 16);
                    }
                }
        }
        __syncthreads();
        if (z == 2) {
            // V in attn-tile layout: Vt[((nh*64 + tI)*32 + d)*32 + key']
            const int c = tid >> 1, half = tid & 1;
            const int coln = bn + c, h = coln >> 5, d = coln & 31;
            const int tI = (wqb + p * 64 + half * 32) >> 5;
            unsigned short* dst =
                &Vt[(((size_t)(n * NHD + h) * 64 + tI) * 32 + d) * 32];
            unsigned hi[16];
            #pragma unroll
            for (int jj = 0; jj < 16; jj++) {
                unsigned u0 = Tp[(half * 32 + 2 * jj    ) * 132 + c];
                unsigned u1 = Tp[(half * 32 + 2 * jj + 1) * 132 + c];
                hi[jj] = __builtin_amdgcn_perm(u1, u0, 0x05040100);
            }
            #pragma unroll
            for (int s = 0; s < 4; s++)
                *(uint4*)&dst[s * 8] = make_uint4(hi[4*s], hi[4*s+1], hi[4*s+2], hi[4*s+3]);
        } else {
            const int lr = tid >> 2, seg = tid & 3;
            const int coln0 = bn + seg * 32, h = coln0 >> 5;
            const size_t off = ((size_t)((n * NHD + h) * WH) + wqb + p * 64 + lr) * DH;
            unsigned short* Thi = (z == 0) ? Qhi : Khi;
            unsigned short* Tlo = (z == 0) ? Qlo : Klo;
            #pragma unroll
            for (int s = 0; s < 4; s++) {
                unsigned u[8], hi[4], lo[4];
                *(uint4*)&u[0] = *(uint4*)&Tp[lr * 132 + seg * 32 + s * 8];
                *(uint4*)&u[4] = *(uint4*)&Tp[lr * 132 + seg * 32 + s * 8 + 4];
                #pragma unroll
                for (int jj = 0; jj < 4; jj++) {
                    hi[jj] = __builtin_amdgcn_perm(u[2*jj+1], u[2*jj], 0x05040100);
                    lo[jj] = __builtin_amdgcn_perm(u[2*jj+1], u[2*jj], 0x07060302);
                }
                *(uint4*)&Thi[off + s * 8] = make_uint4(hi[0], hi[1], hi[2], hi[3]);
                *(uint4*)&Tlo[off + s * 8] = make_uint4(lo[0], lo[1], lo[2], lo[3]);
            }
        }
        __syncthreads();
    }
}

// ---------------- MFMA flash attention (swizzled DMA, conflict-free reads) ----------------
__global__ __launch_bounds__(256, 4) void attn(
    const unsigned short* __restrict__ Qhi, const unsigned short* __restrict__ Qlo,
    const unsigned short* __restrict__ Khi, const unsigned short* __restrict__ Klo,
    const unsigned short* __restrict__ Vt,  const float* __restrict__ X,
    float* __restrict__ Out)
{
    __shared__ __align__(16) unsigned short Kh[2][1024];
    __shared__ __align__(16) unsigned short Kl[2][1024];
    __shared__ __align__(16) unsigned short Vv[2][1024];   // per tile: [d][key32]

    const int tid  = threadIdx.x;
    const int w    = tid >> 6;
    const int lane = tid & 63;
    const int col  = lane & 15;
    const int quad = lane >> 4;
    const int nh   = blockIdx.y;
    const int q0   = blockIdx.x * 128;
    const size_t base = (size_t)nh * WH * DH;

    short8 qh[2], ql[2];
    #pragma unroll
    for (int f = 0; f < 2; f++) {
        const int qrow = q0 + f * 64 + w * 16 + col;
        qh[f] = *(const short8*)&Qhi[base + (size_t)qrow * DH + quad * 8];
        ql[f] = *(const short8*)&Qlo[base + (size_t)qrow * DH + quad * 8];
    }

    f32x4 ot00 = {0.f,0.f,0.f,0.f}, ot01 = {0.f,0.f,0.f,0.f};
    f32x4 ot10 = {0.f,0.f,0.f,0.f}, ot11 = {0.f,0.f,0.f,0.f};
    float mr0 = -INFINITY, mr1 = -INFINITY, lr0 = 0.f, lr1 = 0.f;

    // swizzled gather: lane L -> LDS chunk L, reads logical chunk
    // (row = L>>2, c = (L&3) ^ ((L>>3)&3)) of each 64-chunk segment.
    const size_t toff = (size_t)(lane >> 2) * 64 + (((lane & 3) ^ ((lane >> 3) & 3))) * 16;
    const char* gb;
    unsigned short *ld0, *ld1;
    if (w == 0)      { gb = (const char*)(Khi + base);        ld0 = &Kh[0][0];   ld1 = &Kh[1][0];   }
    else if (w == 1) { gb = (const char*)(Klo + base);        ld0 = &Kl[0][0];   ld1 = &Kl[1][0];   }
    else if (w == 2) { gb = (const char*)(Vt  + base);        ld0 = &Vv[0][0];   ld1 = &Vv[1][0];   }
    else             { gb = (const char*)(Vt  + base) + 1024; ld0 = &Vv[0][512]; ld1 = &Vv[1][512]; }
    gb += toff;

    auto issue = [&](int t, unsigned short* ld) {
        const char* g = gb + (size_t)t * 2048;
        glds16(g, ld);
        if (w < 2) glds16(g + 1024, ld + 512);
    };

    // swizzled fragment offsets (shorts):
    const int sw  = (col >> 1) & 3;
    const int kO0 = col * 32 + (quad ^ sw) * 8;                            // K frag, key=col
    const int vO0 = col * 32 + ((quad >> 1) ^ sw) * 8 + (quad & 1) * 4;    // V frag, keys quad*4..+3
    const int vO1 = col * 32 + ((2 + (quad >> 1)) ^ sw) * 8 + (quad & 1) * 4;

    auto body = [&](int b) {
        const short8 kh0 = *(const short8*)&Kh[b][kO0];
        const short8 kh1 = *(const short8*)&Kh[b][kO0 + 512];
        const short8 kl0 = *(const short8*)&Kl[b][kO0];
        const short8 kl1 = *(const short8*)&Kl[b][kO0 + 512];
        const short4v va00 = *(const short4v*)&Vv[b][vO0];
        const short4v va01 = *(const short4v*)&Vv[b][vO1];
        const short4v va10 = *(const short4v*)&Vv[b][vO0 + 512];
        const short4v va11 = *(const short4v*)&Vv[b][vO1 + 512];

        #pragma unroll
        for (int f = 0; f < 2; f++) {
            f32x4 s0 = {0.f,0.f,0.f,0.f}, s1 = {0.f,0.f,0.f,0.f};
            s0 = __builtin_amdgcn_mfma_f32_16x16x32_bf16(kh0, ql[f], s0, 0, 0, 0);
            s0 = __builtin_amdgcn_mfma_f32_16x16x32_bf16(kl0, qh[f], s0, 0, 0, 0);
            s0 = __builtin_amdgcn_mfma_f32_16x16x32_bf16(kh0, qh[f], s0, 0, 0, 0);
            s1 = __builtin_amdgcn_mfma_f32_16x16x32_bf16(kh1, ql[f], s1, 0, 0, 0);
            s1 = __builtin_amdgcn_mfma_f32_16x16x32_bf16(kl1, qh[f], s1, 0, 0, 0);
            s1 = __builtin_amdgcn_mfma_f32_16x16x32_bf16(kh1, qh[f], s1, 0, 0, 0);

            float mx = fmaxf(fmaxf(fmaxf(s0[0], s0[1]), fmaxf(s0[2], s0[3])),
                             fmaxf(fmaxf(s1[0], s1[1]), fmaxf(s1[2], s1[3])));
            mx = fmaxf(mx, __shfl_xor(mx, 16));
            mx = fmaxf(mx, __shfl_xor(mx, 32));
            float& mrf = f ? mr1 : mr0;
            float& lrf = f ? lr1 : lr0;
            const float mnew  = fmaxf(mrf, mx);
            const float alpha = __builtin_amdgcn_exp2f(mrf - mnew);

            float p0[4], p1[4], ps = 0.f;
            #pragma unroll
            for (int r = 0; r < 4; r++) {
                p0[r] = __builtin_amdgcn_exp2f(s0[r] - mnew); ps += p0[r];
                p1[r] = __builtin_amdgcn_exp2f(s1[r] - mnew); ps += p1[r];
            }
            ps += __shfl_xor(ps, 16);
            ps += __shfl_xor(ps, 32);
            lrf = lrf * alpha + ps;
            mrf = mnew;

            union { short4v v; unsigned u[2]; } Pb0, Pb1;
            Pb0.u[0] = pack_bf16_rn(p0[1], p0[0]);
            Pb0.u[1] = pack_bf16_rn(p0[3], p0[2]);
            Pb1.u[0] = pack_bf16_rn(p1[1], p1[0]);
            Pb1.u[1] = pack_bf16_rn(p1[3], p1[2]);

            f32x4& o0 = f ? ot10 : ot00;
            f32x4& o1 = f ? ot11 : ot01;
            #pragma unroll
            for (int r = 0; r < 4; r++) { o0[r] *= alpha; o1[r] *= alpha; }
            o0 = __builtin_amdgcn_mfma_f32_16x16x16bf16_1k(va00, Pb0.v, o0, 0, 0, 0);
            o0 = __builtin_amdgcn_mfma_f32_16x16x16bf16_1k(va01, Pb1.v, o0, 0, 0, 0);
            o1 = __builtin_amdgcn_mfma_f32_16x16x16bf16_1k(va10, Pb0.v, o1, 0, 0, 0);
            o1 = __builtin_amdgcn_mfma_f32_16x16x16bf16_1k(va11, Pb1.v, o1, 0, 0, 0);
        }
    };

    issue(0, ld0);
    __syncthreads();
    for (int kt2 = 0; kt2 < 32; kt2++) {
        issue(2 * kt2 + 1, ld1);
        body(0);
        __syncthreads();
        if (kt2 < 31) issue(2 * kt2 + 2, ld0);
        body(1);
        __syncthreads();
    }

    // epilogue
    const int n = nh >> 3, h = nh & 7;
    #pragma unroll
    for (int f = 0; f < 2; f++) {
        const float inv = 1.f / (f ? lr1 : lr0);
        const f32x4& o0 = f ? ot10 : ot00;
        const f32x4& o1 = f ? ot11 : ot01;
        const int qrow = q0 + f * 64 + w * 16 + col;
        const size_t a0 = ((size_t)n * WH + qrow) * DM + h * DH + quad * 4;
        float4 x0 = *(const float4*)&X[a0];
        float4 y0;
        y0.x = o0[0] * inv + x0.x;
        y0.y = o0[1] * inv + x0.y;
        y0.z = o0[2] * inv + x0.z;
        y0.w = o0[3] * inv + x0.w;
        *(float4*)&Out[a0] = y0;
        float4 x1 = *(const float4*)&X[a0 + 16];
        float4 y1;
        y1.x = o1[0] * inv + x1.x;
        y1.y = o1[1] * inv + x1.y;
        y1.z = o1[2] * inv + x1.z;
        y1.w = o1[3] * inv + x1.w;
        *(float4*)&Out[a0 + 16] = y1;
    }
}

extern "C" void kernel_launch(void* const* d_in, const int* in_sizes, int n_in,
                              void* d_out, int out_size, void* d_ws, size_t ws_size,
                              hipStream_t stream) {
    const float* x  = (const float*)d_in[0];
    const float* Wq = (const float*)d_in[1];
    const float* bq = (const float*)d_in[2];
    const float* Wk = (const float*)d_in[3];
    const float* bk = (const float*)d_in[4];
    const float* Wv = (const float*)d_in[5];
    const float* bv = (const float*)d_in[6];
    float* out = (float*)d_out;

    const size_t elems = (size_t)NB * WH * DM;   // 4,194,304
    unsigned short* Qhi  = (unsigned short*)d_ws;
    unsigned short* Qlo  = Qhi + elems;
    unsigned short* Khi  = Qlo + elems;
    unsigned short* Klo  = Khi + elems;
    unsigned short* Vt   = Klo + elems;
    unsigned short* WThi = Vt  + elems;
    unsigned short* WTlo = WThi + (size_t)3 * DM * DM;

    // X hi/lo split lives in d_out (16.78 MB); attn fully overwrites d_out after.
    unsigned short* Xhi = (unsigned short*)d_out;
    unsigned short* Xlo = Xhi + elems;

    xprep<<<2048, 256, 0, stream>>>(x, Xhi, Xlo);

    dim3 gw(16, 3);
    wprep<<<gw, 256, 0, stream>>>(Wq, Wk, Wv, WThi, WTlo);

    dim3 gg(128, 2, 3);
    qkv_mfma<<<gg, 256, 0, stream>>>(Xhi, Xlo, WThi, WTlo, bq, bk, bv,
                                     Qhi, Qlo, Khi, Klo, Vt);

    dim3 ga(WH / 128, NB * NHD);   // (16, 64) = 1024 blocks
    attn<<<ga, 256, 0, stream>>>(Qhi, Qlo, Khi, Klo, Vt, x, out);
}

// Round 8
// 217.828 us; speedup vs baseline: 4.6471x; 1.0680x over previous
//
#include <hip/hip_runtime.h>
#include <math.h>

// MHSA round 8: contiguous-DMA layouts everywhere.
//  - Xhi/Xlo, WThi/WTlo stored in k-slab layout [kb][row][32] -> 8KB-contiguous tiles.
//  - K/V stored as per-64-key blobs [Khi 64x32 | Klo 64x32 | V 32dx64k] (12KB).
//  - attn: 64-key tiles, lane-local l, per-section XOR swizzles, 24KB LDS.
#define WH 2048
#define DM 256
#define NHD 8
#define DH 32
#define NB 8

typedef __attribute__((ext_vector_type(8))) short short8;
typedef __attribute__((ext_vector_type(4))) short short4v;
typedef __attribute__((ext_vector_type(4))) float f32x4;

__device__ __forceinline__ unsigned short bf16_rn(float f) {
    unsigned u = __float_as_uint(f);
    return (unsigned short)((u + 0x8000u) >> 16);
}
__device__ __forceinline__ float bf16_to_f(unsigned short h) {
    return __uint_as_float(((unsigned)h) << 16);
}
__device__ __forceinline__ unsigned pack_bf16_rn(float f1, float f0) {
    return __builtin_amdgcn_perm(__float_as_uint(f1) + 0x8000u,
                                 __float_as_uint(f0) + 0x8000u, 0x07060302);
}
__device__ __forceinline__ void glds16(const void* g, void* l) {
    __builtin_amdgcn_global_load_lds(
        (const __attribute__((address_space(1))) unsigned int*)g,
        (__attribute__((address_space(3))) unsigned int*)l, 16, 0, 0);
}

// ---------------- X prep: fp32 -> bf16 hi/lo, k-slab layout [kb][row16384][32] ----------------
__global__ __launch_bounds__(256) void xprep(
    const float* __restrict__ X,
    unsigned short* __restrict__ Xhi, unsigned short* __restrict__ Xlo)
{
    const size_t i = ((size_t)blockIdx.x * 256 + threadIdx.x) * 8;
    const int row = (int)(i >> 8);
    const int k   = (int)(i & 255);
    const size_t dst = ((size_t)(k >> 5) * 16384 + row) * 32 + (k & 31);
    float4 a = *(const float4*)&X[i];
    float4 b = *(const float4*)&X[i + 4];
    float v[8] = {a.x, a.y, a.z, a.w, b.x, b.y, b.z, b.w};
    short8 hi, lo;
    #pragma unroll
    for (int e = 0; e < 8; e++) {
        unsigned short hb = bf16_rn(v[e]);
        hi[e] = (short)hb;
        lo[e] = (short)bf16_rn(v[e] - bf16_to_f(hb));
    }
    *(short8*)&Xhi[dst] = hi;
    *(short8*)&Xlo[dst] = lo;
}

// ---------------- W prep: transpose + split, k-slab layout [z][kb][col256][32] ----------------
__global__ __launch_bounds__(256) void wprep(
    const float* __restrict__ Wq, const float* __restrict__ Wk,
    const float* __restrict__ Wv,
    unsigned short* __restrict__ WThi, unsigned short* __restrict__ WTlo)
{
    const int z = blockIdx.y;
    const float* W = (z == 0) ? Wq : ((z == 1) ? Wk : Wv);
    const size_t zoff = (size_t)z * DM * DM;
    const int tg = blockIdx.x * 256 + threadIdx.x;
    #pragma unroll
    for (int j = 0; j < 4; j++) {
        const int f = tg + j * 4096;
        const int k  = f >> 6;
        const int n0 = (f & 63) * 4;
        float4 v = *(const float4*)&W[(size_t)k * DM + n0];
        float vv[4] = {v.x, v.y, v.z, v.w};
        #pragma unroll
        for (int i = 0; i < 4; i++) {
            unsigned short hb = bf16_rn(vv[i]);
            const size_t dst = zoff + ((size_t)(k >> 5) * 256 + n0 + i) * 32 + (k & 31);
            WThi[dst] = hb;
            WTlo[dst] = bf16_rn(vv[i] - bf16_to_f(hb));
        }
    }
}

// ---------------- QKV projection: split-bf16 MFMA, contiguous DMA dbuf ----------------
__global__ __launch_bounds__(256, 1) void qkv_mfma(
    const unsigned short* __restrict__ Xhi, const unsigned short* __restrict__ Xlo,
    const unsigned short* __restrict__ WThi, const unsigned short* __restrict__ WTlo,
    const float* __restrict__ bq, const float* __restrict__ bk, const float* __restrict__ bv,
    unsigned short* __restrict__ Qhi, unsigned short* __restrict__ Qlo,
    unsigned short* __restrict__ KV)
{
    // arena: 4 arrays x 2 buffers x 4096 shorts = 64 KB; epilogue reuses it.
    __shared__ __align__(16) unsigned short arena[4 * 2 * 4096];

    const int z = blockIdx.z;
    const float* bias = (z == 0) ? bq : ((z == 1) ? bk : bv);
    const size_t zoff = (size_t)z * DM * DM;

    const int tid  = threadIdx.x;
    const int w    = tid >> 6;
    const int lane = tid & 63;
    const int col  = lane & 15;
    const int quad = lane >> 4;
    const int wr = w >> 1, wc = w & 1;
    const int bm = blockIdx.x * 128;
    const int bn = blockIdx.y * 128;

    // contiguous 8KB tile gather; swizzle: physical chunk L <- logical (L&3)^((L>>3)&3)
    const int perm16 = (((lane & 3) ^ ((lane >> 3) & 3))) * 16;
    const char* glane; size_t kstr;
    if (w == 0)      { glane = (const char*)Xhi + (size_t)(bm + (lane >> 2)) * 64 + perm16; kstr = (size_t)16384 * 64; }
    else if (w == 1) { glane = (const char*)Xlo + (size_t)(bm + (lane >> 2)) * 64 + perm16; kstr = (size_t)16384 * 64; }
    else if (w == 2) { glane = (const char*)(WThi + zoff) + (size_t)(bn + (lane >> 2)) * 64 + perm16; kstr = 256 * 64; }
    else             { glane = (const char*)(WTlo + zoff) + (size_t)(bn + (lane >> 2)) * 64 + perm16; kstr = 256 * 64; }

    auto issue = [&](int kb, int b) {
        const char* g0 = glane + (size_t)kb * kstr;
        unsigned short* l0 = &arena[w * 8192 + b * 4096];
        #pragma unroll
        for (int g = 0; g < 8; g++)
            glds16(g0 + (size_t)g * 1024, l0 + g * 512);
    };

    f32x4 acc[4][4];
    #pragma unroll
    for (int mi = 0; mi < 4; mi++)
        #pragma unroll
        for (int ni = 0; ni < 4; ni++) acc[mi][ni] = (f32x4){0.f, 0.f, 0.f, 0.f};

    const int sw = (col >> 1) & 3;
    const int fO = (quad ^ sw) * 8;

    issue(0, 0);
    __syncthreads();
    for (int kb = 0; kb < 8; kb++) {
        const int b = kb & 1;
        if (kb < 7) issue(kb + 1, b ^ 1);

        short8 ah[4], al[4], bh[4], bl[4];
        #pragma unroll
        for (int mi = 0; mi < 4; mi++) {
            const int ro = (wr * 64 + mi * 16 + col) * 32 + fO;
            ah[mi] = *(const short8*)&arena[        b * 4096 + ro];
            al[mi] = *(const short8*)&arena[ 8192 + b * 4096 + ro];
        }
        #pragma unroll
        for (int ni = 0; ni < 4; ni++) {
            const int no = (wc * 64 + ni * 16 + col) * 32 + fO;
            bh[ni] = *(const short8*)&arena[16384 + b * 4096 + no];
            bl[ni] = *(const short8*)&arena[24576 + b * 4096 + no];
        }
        #pragma unroll
        for (int mi = 0; mi < 4; mi++)
            #pragma unroll
            for (int ni = 0; ni < 4; ni++) {
                acc[mi][ni] = __builtin_amdgcn_mfma_f32_16x16x32_bf16(al[mi], bh[ni], acc[mi][ni], 0, 0, 0);
                acc[mi][ni] = __builtin_amdgcn_mfma_f32_16x16x32_bf16(ah[mi], bl[ni], acc[mi][ni], 0, 0, 0);
                acc[mi][ni] = __builtin_amdgcn_mfma_f32_16x16x32_bf16(ah[mi], bh[ni], acc[mi][ni], 0, 0, 0);
            }
        __syncthreads();
    }

    // ---- vectorized epilogue through LDS (packed hi|lo uints) ----
    unsigned* Tp = (unsigned*)arena;                 // [64][132]
    const int n   = bm >> 11;
    const int wqb = bm & (WH - 1);
    const float qsc = (z == 0) ? 8.1611159f : 1.0f;  // sqrt(32)*log2(e) folded into Q

    #pragma unroll
    for (int p = 0; p < 2; p++) {
        if (wr == p) {
            #pragma unroll
            for (int mi = 0; mi < 4; mi++)
                #pragma unroll
                for (int ni = 0; ni < 4; ni++) {
                    const int lc = wc * 64 + ni * 16 + col;
                    const float bb = bias[bn + lc];
                    #pragma unroll
                    for (int r = 0; r < 4; r++) {
                        float v = (acc[mi][ni][r] + bb) * qsc;
                        unsigned short hb = bf16_rn(v);
                        unsigned short lb = bf16_rn(v - bf16_to_f(hb));
                        Tp[(mi * 16 + quad * 4 + r) * 132 + lc] =
                            (unsigned)hb | ((unsigned)lb << 16);
                    }
                }
        }
        __syncthreads();
        if (z == 2) {
            // V section of the blob: KV[blob + 4096 + d*64 + k6], 64B/thread
            const int c = tid >> 1, half = tid & 1;
            const int coln = bn + c, h = coln >> 5, d = coln & 31;
            const int key0 = wqb + p * 64 + half * 32;
            const int t = key0 >> 6, k6 = key0 & 63;
            unsigned short* dst =
                &KV[(((size_t)(n * NHD + h) * 32 + t) * 6144) + 4096 + d * 64 + k6];
            unsigned hi[16];
            #pragma unroll
            for (int jj = 0; jj < 16; jj++) {
                unsigned u0 = Tp[(half * 32 + 2 * jj    ) * 132 + c];
                unsigned u1 = Tp[(half * 32 + 2 * jj + 1) * 132 + c];
                hi[jj] = __builtin_amdgcn_perm(u1, u0, 0x05040100);
            }
            #pragma unroll
            for (int s = 0; s < 4; s++)
                *(uint4*)&dst[s * 8] = make_uint4(hi[4*s], hi[4*s+1], hi[4*s+2], hi[4*s+3]);
        } else if (z == 1) {
            // K sections of the blob: Khi at +0, Klo at +2048
            const int lr = tid >> 2, seg = tid & 3;
            const int h = (bn + seg * 32) >> 5;
            const int key = wqb + p * 64 + lr;
            const int t = key >> 6, k6 = key & 63;
            unsigned short* blobK =
                &KV[(((size_t)(n * NHD + h) * 32 + t) * 6144) + k6 * 32];
            #pragma unroll
            for (int s = 0; s < 4; s++) {
                unsigned u[8], hi[4], lo[4];
                *(uint4*)&u[0] = *(uint4*)&Tp[lr * 132 + seg * 32 + s * 8];
                *(uint4*)&u[4] = *(uint4*)&Tp[lr * 132 + seg * 32 + s * 8 + 4];
                #pragma unroll
                for (int jj = 0; jj < 4; jj++) {
                    hi[jj] = __builtin_amdgcn_perm(u[2*jj+1], u[2*jj], 0x05040100);
                    lo[jj] = __builtin_amdgcn_perm(u[2*jj+1], u[2*jj], 0x07060302);
                }
                *(uint4*)&blobK[s * 8]        = make_uint4(hi[0], hi[1], hi[2], hi[3]);
                *(uint4*)&blobK[2048 + s * 8] = make_uint4(lo[0], lo[1], lo[2], lo[3]);
            }
        } else {
            // Q: row-major hi/lo as before
            const int lr = tid >> 2, seg = tid & 3;
            const int h = (bn + seg * 32) >> 5;
            const size_t off = ((size_t)((n * NHD + h) * WH) + wqb + p * 64 + lr) * DH;
            #pragma unroll
            for (int s = 0; s < 4; s++) {
                unsigned u[8], hi[4], lo[4];
                *(uint4*)&u[0] = *(uint4*)&Tp[lr * 132 + seg * 32 + s * 8];
                *(uint4*)&u[4] = *(uint4*)&Tp[lr * 132 + seg * 32 + s * 8 + 4];
                #pragma unroll
                for (int jj = 0; jj < 4; jj++) {
                    hi[jj] = __builtin_amdgcn_perm(u[2*jj+1], u[2*jj], 0x05040100);
                    lo[jj] = __builtin_amdgcn_perm(u[2*jj+1], u[2*jj], 0x07060302);
                }
                *(uint4*)&Qhi[off + s * 8] = make_uint4(hi[0], hi[1], hi[2], hi[3]);
                *(uint4*)&Qlo[off + s * 8] = make_uint4(lo[0], lo[1], lo[2], lo[3]);
            }
        }
        __syncthreads();
    }
}

// ---------------- MFMA flash attention: 64-key blob tiles ----------------
__global__ __launch_bounds__(256, 4) void attn(
    const unsigned short* __restrict__ Qhi, const unsigned short* __restrict__ Qlo,
    const unsigned short* __restrict__ KV,  const float* __restrict__ X,
    float* __restrict__ Out)
{
    __shared__ __align__(16) unsigned short B[2][6144];   // 12KB blob x2

    const int tid  = threadIdx.x;
    const int w    = tid >> 6;
    const int lane = tid & 63;
    const int col  = lane & 15;
    const int quad = lane >> 4;
    const int nh   = blockIdx.y;
    const int q0   = blockIdx.x * 128;
    const size_t qbase = (size_t)nh * WH * DH;
    const char* blob = (const char*)(KV + (size_t)nh * 196608);

    short8 qh[2], ql[2];
    #pragma unroll
    for (int f = 0; f < 2; f++) {
        const int qrow = q0 + f * 64 + w * 16 + col;
        qh[f] = *(const short8*)&Qhi[qbase + (size_t)qrow * DH + quad * 8];
        ql[f] = *(const short8*)&Qlo[qbase + (size_t)qrow * DH + quad * 8];
    }

    f32x4 o00 = {0.f,0.f,0.f,0.f}, o01 = {0.f,0.f,0.f,0.f};
    f32x4 o10 = {0.f,0.f,0.f,0.f}, o11 = {0.f,0.f,0.f,0.f};
    float mr0 = -INFINITY, mr1 = -INFINITY, lr0 = 0.f, lr1 = 0.f;

    // per-wave 3 DMA segments of the 12KB blob tile
    const char* gseg[3];
    int loseg[3];
    #pragma unroll
    for (int j = 0; j < 3; j++) {
        const int s = w * 3 + j;
        int loff;
        if (s < 8) loff = (lane >> 2) * 64  + (((lane & 3) ^ ((lane >> 3) & 3)) << 4);
        else       loff = (lane >> 3) * 128 + (((lane & 7) ^ ((lane >> 3) & 7)) << 4);
        gseg[j] = blob + s * 1024 + loff;
        loseg[j] = s * 512;
    }

    auto issue = [&](int t, int b) {
        #pragma unroll
        for (int j = 0; j < 3; j++)
            glds16(gseg[j] + (size_t)t * 12288, &B[b][loseg[j]]);
    };

    const int sw = (col >> 1) & 3;

    auto body = [&](int b) {
        const unsigned short* Bp = &B[b][0];
        short8 kh[4], kl[4];
        #pragma unroll
        for (int kc = 0; kc < 4; kc++) {
            const int ro = (col + kc * 16) * 32 + (quad ^ sw) * 8;
            kh[kc] = *(const short8*)&Bp[ro];
            kl[kc] = *(const short8*)&Bp[2048 + ro];
        }
        short4v va[4][2];
        #pragma unroll
        for (int kc = 0; kc < 4; kc++) {
            const int cl = kc * 2 + (quad >> 1);
            const int co = ((cl ^ (col & 7)) << 3) + (quad & 1) * 4;
            va[kc][0] = *(const short4v*)&Bp[4096 + (col     ) * 64 + co];
            va[kc][1] = *(const short4v*)&Bp[4096 + (col + 16) * 64 + co];
        }
        #pragma unroll
        for (int f = 0; f < 2; f++) {
            f32x4 s[4];
            #pragma unroll
            for (int kc = 0; kc < 4; kc++) {
                f32x4 a = {0.f, 0.f, 0.f, 0.f};
                a = __builtin_amdgcn_mfma_f32_16x16x32_bf16(kh[kc], ql[f], a, 0, 0, 0);
                a = __builtin_amdgcn_mfma_f32_16x16x32_bf16(kl[kc], qh[f], a, 0, 0, 0);
                a = __builtin_amdgcn_mfma_f32_16x16x32_bf16(kh[kc], qh[f], a, 0, 0, 0);
                s[kc] = a;
            }
            float mx = s[0][0];
            #pragma unroll
            for (int kc = 0; kc < 4; kc++)
                #pragma unroll
                for (int r = 0; r < 4; r++) mx = fmaxf(mx, s[kc][r]);
            mx = fmaxf(mx, __shfl_xor(mx, 16));
            mx = fmaxf(mx, __shfl_xor(mx, 32));
            float& mrf = f ? mr1 : mr0;
            float& lrf = f ? lr1 : lr0;
            const float mnew  = fmaxf(mrf, mx);
            const float alpha = __builtin_amdgcn_exp2f(mrf - mnew);

            float ps = 0.f;
            #pragma unroll
            for (int kc = 0; kc < 4; kc++)
                #pragma unroll
                for (int r = 0; r < 4; r++) {
                    s[kc][r] = __builtin_amdgcn_exp2f(s[kc][r] - mnew);
                    ps += s[kc][r];
                }
            lrf = lrf * alpha + ps;   // lane-local partial; reduced after loop
            mrf = mnew;

            short4v pb[4];
            #pragma unroll
            for (int kc = 0; kc < 4; kc++) {
                union { short4v v; unsigned u[2]; } P;
                P.u[0] = pack_bf16_rn(s[kc][1], s[kc][0]);
                P.u[1] = pack_bf16_rn(s[kc][3], s[kc][2]);
                pb[kc] = P.v;
            }

            f32x4& a0 = f ? o10 : o00;
            f32x4& a1 = f ? o11 : o01;
            #pragma unroll
            for (int r = 0; r < 4; r++) { a0[r] *= alpha; a1[r] *= alpha; }
            #pragma unroll
            for (int kc = 0; kc < 4; kc++) {
                a0 = __builtin_amdgcn_mfma_f32_16x16x16bf16_1k(va[kc][0], pb[kc], a0, 0, 0, 0);
                a1 = __builtin_amdgcn_mfma_f32_16x16x16bf16_1k(va[kc][1], pb[kc], a1, 0, 0, 0);
            }
        }
    };

    issue(0, 0);
    __syncthreads();
    for (int t2 = 0; t2 < 16; t2++) {
        issue(2 * t2 + 1, 1);
        body(0);
        __syncthreads();
        if (t2 < 15) issue(2 * t2 + 2, 0);
        body(1);
        __syncthreads();
    }

    // reduce lane-local l across quads, then epilogue
    const int n = nh >> 3, h = nh & 7;
    #pragma unroll
    for (int f = 0; f < 2; f++) {
        float l = f ? lr1 : lr0;
        l += __shfl_xor(l, 16);
        l += __shfl_xor(l, 32);
        const float inv = 1.f / l;
        const f32x4& a0 = f ? o10 : o00;
        const f32x4& a1 = f ? o11 : o01;
        const int qrow = q0 + f * 64 + w * 16 + col;
        const size_t a = ((size_t)n * WH + qrow) * DM + h * DH + quad * 4;
        float4 x0 = *(const float4*)&X[a];
        float4 y0;
        y0.x = a0[0] * inv + x0.x;
        y0.y = a0[1] * inv + x0.y;
        y0.z = a0[2] * inv + x0.z;
        y0.w = a0[3] * inv + x0.w;
        *(float4*)&Out[a] = y0;
        float4 x1 = *(const float4*)&X[a + 16];
        float4 y1;
        y1.x = a1[0] * inv + x1.x;
        y1.y = a1[1] * inv + x1.y;
        y1.z = a1[2] * inv + x1.z;
        y1.w = a1[3] * inv + x1.w;
        *(float4*)&Out[a + 16] = y1;
    }
}

extern "C" void kernel_launch(void* const* d_in, const int* in_sizes, int n_in,
                              void* d_out, int out_size, void* d_ws, size_t ws_size,
                              hipStream_t stream) {
    const float* x  = (const float*)d_in[0];
    const float* Wq = (const float*)d_in[1];
    const float* bq = (const float*)d_in[2];
    const float* Wk = (const float*)d_in[3];
    const float* bk = (const float*)d_in[4];
    const float* Wv = (const float*)d_in[5];
    const float* bv = (const float*)d_in[6];
    float* out = (float*)d_out;

    const size_t elems = (size_t)NB * WH * DM;   // 4,194,304
    unsigned short* Qhi  = (unsigned short*)d_ws;
    unsigned short* Qlo  = Qhi + elems;
    unsigned short* KV   = Qlo + elems;                    // 64 heads x 32 tiles x 6144
    unsigned short* WThi = KV  + (size_t)64 * 32 * 6144;
    unsigned short* WTlo = WThi + (size_t)3 * DM * DM;

    // X hi/lo slabs live in d_out (16.78 MB); attn fully overwrites d_out after.
    unsigned short* Xhi = (unsigned short*)d_out;
    unsigned short* Xlo = Xhi + elems;

    xprep<<<2048, 256, 0, stream>>>(x, Xhi, Xlo);

    dim3 gw(16, 3);
    wprep<<<gw, 256, 0, stream>>>(Wq, Wk, Wv, WThi, WTlo);

    dim3 gg(128, 2, 3);
    qkv_mfma<<<gg, 256, 0, stream>>>(Xhi, Xlo, WThi, WTlo, bq, bk, bv,
                                     Qhi, Qlo, KV);

    dim3 ga(WH / 128, NB * NHD);   // (16, 64) = 1024 blocks
    attn<<<ga, 256, 0, stream>>>(Qhi, Qlo, KV, x, out);
}

// Round 9
// 202.838 us; speedup vs baseline: 4.9905x; 1.0739x over previous
//
#include <hip/hip_runtime.h>
#include <math.h>

// MHSA round 9: attn VALU diet (l-via-MFMA, RTZ pack, lazy rescale) +
// qkv single-buffer (3 blocks/CU) + merged prep kernel.
#define WH 2048
#define DM 256
#define NHD 8
#define DH 32
#define NB 8

typedef __attribute__((ext_vector_type(8))) short short8;
typedef __attribute__((ext_vector_type(4))) short short4v;
typedef __attribute__((ext_vector_type(4))) float f32x4;

__device__ __forceinline__ unsigned short bf16_rn(float f) {
    unsigned u = __float_as_uint(f);
    return (unsigned short)((u + 0x8000u) >> 16);
}
__device__ __forceinline__ float bf16_to_f(unsigned short h) {
    return __uint_as_float(((unsigned)h) << 16);
}
__device__ __forceinline__ unsigned pack_bf16_rtz(float f1, float f0) {
    return __builtin_amdgcn_perm(__float_as_uint(f1), __float_as_uint(f0), 0x07060302);
}
__device__ __forceinline__ void glds16(const void* g, void* l) {
    __builtin_amdgcn_global_load_lds(
        (const __attribute__((address_space(1))) unsigned int*)g,
        (__attribute__((address_space(3))) unsigned int*)l, 16, 0, 0);
}

// ---------------- prep: X split (blocks 0..2047) + W transpose/split (2048..2095) ----------------
__global__ __launch_bounds__(256) void prep(
    const float* __restrict__ X,
    const float* __restrict__ Wq, const float* __restrict__ Wk, const float* __restrict__ Wv,
    unsigned short* __restrict__ Xhi, unsigned short* __restrict__ Xlo,
    unsigned short* __restrict__ WThi, unsigned short* __restrict__ WTlo)
{
    const int bid = blockIdx.x;
    if (bid < 2048) {
        const size_t i = ((size_t)bid * 256 + threadIdx.x) * 8;
        const int row = (int)(i >> 8);
        const int k   = (int)(i & 255);
        const size_t dst = ((size_t)(k >> 5) * 16384 + row) * 32 + (k & 31);
        float4 a = *(const float4*)&X[i];
        float4 b = *(const float4*)&X[i + 4];
        float v[8] = {a.x, a.y, a.z, a.w, b.x, b.y, b.z, b.w};
        short8 hi, lo;
        #pragma unroll
        for (int e = 0; e < 8; e++) {
            unsigned short hb = bf16_rn(v[e]);
            hi[e] = (short)hb;
            lo[e] = (short)bf16_rn(v[e] - bf16_to_f(hb));
        }
        *(short8*)&Xhi[dst] = hi;
        *(short8*)&Xlo[dst] = lo;
    } else {
        const int b2 = bid - 2048;           // 0..47
        const int z = b2 >> 4, xb = b2 & 15;
        const float* W = (z == 0) ? Wq : ((z == 1) ? Wk : Wv);
        const size_t zoff = (size_t)z * DM * DM;
        const int tg = xb * 256 + threadIdx.x;
        #pragma unroll
        for (int j = 0; j < 4; j++) {
            const int f = tg + j * 4096;
            const int k  = f >> 6;
            const int n0 = (f & 63) * 4;
            float4 v = *(const float4*)&W[(size_t)k * DM + n0];
            float vv[4] = {v.x, v.y, v.z, v.w};
            #pragma unroll
            for (int i = 0; i < 4; i++) {
                unsigned short hb = bf16_rn(vv[i]);
                const size_t dst = zoff + ((size_t)(k >> 5) * 256 + n0 + i) * 32 + (k & 31);
                WThi[dst] = hb;
                WTlo[dst] = bf16_rn(vv[i] - bf16_to_f(hb));
            }
        }
    }
}

// ---------------- QKV projection: split-bf16 MFMA, single-buffer DMA ----------------
__global__ __launch_bounds__(256, 3) void qkv_mfma(
    const unsigned short* __restrict__ Xhi, const unsigned short* __restrict__ Xlo,
    const unsigned short* __restrict__ WThi, const unsigned short* __restrict__ WTlo,
    const float* __restrict__ bq, const float* __restrict__ bk, const float* __restrict__ bv,
    unsigned short* __restrict__ Qhi, unsigned short* __restrict__ Qlo,
    unsigned short* __restrict__ KV)
{
    // arena: staging 4 x 4096 shorts (32KB); epilogue Tp 64x132 uints (33.8KB)
    __shared__ __align__(16) unsigned short arena[16896];

    const int z = blockIdx.z;
    const float* bias = (z == 0) ? bq : ((z == 1) ? bk : bv);
    const size_t zoff = (size_t)z * DM * DM;

    const int tid  = threadIdx.x;
    const int w    = tid >> 6;
    const int lane = tid & 63;
    const int col  = lane & 15;
    const int quad = lane >> 4;
    const int wr = w >> 1, wc = w & 1;
    const int bm = blockIdx.x * 128;
    const int bn = blockIdx.y * 128;

    const int perm16 = (((lane & 3) ^ ((lane >> 3) & 3))) * 16;
    const char* glane; size_t kstr;
    if (w == 0)      { glane = (const char*)Xhi + (size_t)(bm + (lane >> 2)) * 64 + perm16; kstr = (size_t)16384 * 64; }
    else if (w == 1) { glane = (const char*)Xlo + (size_t)(bm + (lane >> 2)) * 64 + perm16; kstr = (size_t)16384 * 64; }
    else if (w == 2) { glane = (const char*)(WThi + zoff) + (size_t)(bn + (lane >> 2)) * 64 + perm16; kstr = 256 * 64; }
    else             { glane = (const char*)(WTlo + zoff) + (size_t)(bn + (lane >> 2)) * 64 + perm16; kstr = 256 * 64; }

    auto issue = [&](int kb) {
        const char* g0 = glane + (size_t)kb * kstr;
        unsigned short* l0 = &arena[w * 4096];
        #pragma unroll
        for (int g = 0; g < 8; g++)
            glds16(g0 + (size_t)g * 1024, l0 + g * 512);
    };

    f32x4 acc[4][4];
    #pragma unroll
    for (int mi = 0; mi < 4; mi++)
        #pragma unroll
        for (int ni = 0; ni < 4; ni++) acc[mi][ni] = (f32x4){0.f, 0.f, 0.f, 0.f};

    const int sw = (col >> 1) & 3;
    const int fO = (quad ^ sw) * 8;

    for (int kb = 0; kb < 8; kb++) {
        issue(kb);
        __syncthreads();

        short8 ah[4], al[4], bh[4], bl[4];
        #pragma unroll
        for (int mi = 0; mi < 4; mi++) {
            const int ro = (wr * 64 + mi * 16 + col) * 32 + fO;
            ah[mi] = *(const short8*)&arena[ro];
            al[mi] = *(const short8*)&arena[4096 + ro];
        }
        #pragma unroll
        for (int ni = 0; ni < 4; ni++) {
            const int no = (wc * 64 + ni * 16 + col) * 32 + fO;
            bh[ni] = *(const short8*)&arena[8192 + no];
            bl[ni] = *(const short8*)&arena[12288 + no];
        }
        #pragma unroll
        for (int mi = 0; mi < 4; mi++)
            #pragma unroll
            for (int ni = 0; ni < 4; ni++) {
                acc[mi][ni] = __builtin_amdgcn_mfma_f32_16x16x32_bf16(al[mi], bh[ni], acc[mi][ni], 0, 0, 0);
                acc[mi][ni] = __builtin_amdgcn_mfma_f32_16x16x32_bf16(ah[mi], bl[ni], acc[mi][ni], 0, 0, 0);
                acc[mi][ni] = __builtin_amdgcn_mfma_f32_16x16x32_bf16(ah[mi], bh[ni], acc[mi][ni], 0, 0, 0);
            }
        __syncthreads();
    }

    // ---- vectorized epilogue through LDS (packed hi|lo uints) ----
    unsigned* Tp = (unsigned*)arena;                 // [64][132]
    const int n   = bm >> 11;
    const int wqb = bm & (WH - 1);
    const float qsc = (z == 0) ? 8.1611159f : 1.0f;  // sqrt(32)*log2(e) folded into Q

    #pragma unroll
    for (int p = 0; p < 2; p++) {
        if (wr == p) {
            #pragma unroll
            for (int mi = 0; mi < 4; mi++)
                #pragma unroll
                for (int ni = 0; ni < 4; ni++) {
                    const int lc = wc * 64 + ni * 16 + col;
                    const float bb = bias[bn + lc];
                    #pragma unroll
                    for (int r = 0; r < 4; r++) {
                        float v = (acc[mi][ni][r] + bb) * qsc;
                        unsigned short hb = bf16_rn(v);
                        unsigned short lb = bf16_rn(v - bf16_to_f(hb));
                        Tp[(mi * 16 + quad * 4 + r) * 132 + lc] =
                            (unsigned)hb | ((unsigned)lb << 16);
                    }
                }
        }
        __syncthreads();
        if (z == 2) {
            const int c = tid >> 1, half = tid & 1;
            const int coln = bn + c, h = coln >> 5, d = coln & 31;
            const int key0 = wqb + p * 64 + half * 32;
            const int t = key0 >> 6, k6 = key0 & 63;
            unsigned short* dst =
                &KV[(((size_t)(n * NHD + h) * 32 + t) * 6144) + 4096 + d * 64 + k6];
            unsigned hi[16];
            #pragma unroll
            for (int jj = 0; jj < 16; jj++) {
                unsigned u0 = Tp[(half * 32 + 2 * jj    ) * 132 + c];
                unsigned u1 = Tp[(half * 32 + 2 * jj + 1) * 132 + c];
                hi[jj] = __builtin_amdgcn_perm(u1, u0, 0x05040100);
            }
            #pragma unroll
            for (int s = 0; s < 4; s++)
                *(uint4*)&dst[s * 8] = make_uint4(hi[4*s], hi[4*s+1], hi[4*s+2], hi[4*s+3]);
        } else if (z == 1) {
            const int lr = tid >> 2, seg = tid & 3;
            const int h = (bn + seg * 32) >> 5;
            const int key = wqb + p * 64 + lr;
            const int t = key >> 6, k6 = key & 63;
            unsigned short* blobK =
                &KV[(((size_t)(n * NHD + h) * 32 + t) * 6144) + k6 * 32];
            #pragma unroll
            for (int s = 0; s < 4; s++) {
                unsigned u[8], hi[4], lo[4];
                *(uint4*)&u[0] = *(uint4*)&Tp[lr * 132 + seg * 32 + s * 8];
                *(uint4*)&u[4] = *(uint4*)&Tp[lr * 132 + seg * 32 + s * 8 + 4];
                #pragma unroll
                for (int jj = 0; jj < 4; jj++) {
                    hi[jj] = __builtin_amdgcn_perm(u[2*jj+1], u[2*jj], 0x05040100);
                    lo[jj] = __builtin_amdgcn_perm(u[2*jj+1], u[2*jj], 0x07060302);
                }
                *(uint4*)&blobK[s * 8]        = make_uint4(hi[0], hi[1], hi[2], hi[3]);
                *(uint4*)&blobK[2048 + s * 8] = make_uint4(lo[0], lo[1], lo[2], lo[3]);
            }
        } else {
            const int lr = tid >> 2, seg = tid & 3;
            const int h = (bn + seg * 32) >> 5;
            const size_t off = ((size_t)((n * NHD + h) * WH) + wqb + p * 64 + lr) * DH;
            #pragma unroll
            for (int s = 0; s < 4; s++) {
                unsigned u[8], hi[4], lo[4];
                *(uint4*)&u[0] = *(uint4*)&Tp[lr * 132 + seg * 32 + s * 8];
                *(uint4*)&u[4] = *(uint4*)&Tp[lr * 132 + seg * 32 + s * 8 + 4];
                #pragma unroll
                for (int jj = 0; jj < 4; jj++) {
                    hi[jj] = __builtin_amdgcn_perm(u[2*jj+1], u[2*jj], 0x05040100);
                    lo[jj] = __builtin_amdgcn_perm(u[2*jj+1], u[2*jj], 0x07060302);
                }
                *(uint4*)&Qhi[off + s * 8] = make_uint4(hi[0], hi[1], hi[2], hi[3]);
                *(uint4*)&Qlo[off + s * 8] = make_uint4(lo[0], lo[1], lo[2], lo[3]);
            }
        }
        __syncthreads();
    }
}

// ---------------- MFMA flash attention: 64-key blob tiles, VALU diet ----------------
__global__ __launch_bounds__(256, 4) void attn(
    const unsigned short* __restrict__ Qhi, const unsigned short* __restrict__ Qlo,
    const unsigned short* __restrict__ KV,  const float* __restrict__ X,
    float* __restrict__ Out)
{
    __shared__ __align__(16) unsigned short B[2][6144];   // 12KB blob x2

    const int tid  = threadIdx.x;
    const int w    = tid >> 6;
    const int lane = tid & 63;
    const int col  = lane & 15;
    const int quad = lane >> 4;
    const int nh   = blockIdx.y;
    const int q0   = blockIdx.x * 128;
    const size_t qbase = (size_t)nh * WH * DH;
    const char* blob = (const char*)(KV + (size_t)nh * 196608);

    short8 qh[2], ql[2];
    #pragma unroll
    for (int f = 0; f < 2; f++) {
        const int qrow = q0 + f * 64 + w * 16 + col;
        qh[f] = *(const short8*)&Qhi[qbase + (size_t)qrow * DH + quad * 8];
        ql[f] = *(const short8*)&Qlo[qbase + (size_t)qrow * DH + quad * 8];
    }

    f32x4 o00 = {0.f,0.f,0.f,0.f}, o01 = {0.f,0.f,0.f,0.f};
    f32x4 o10 = {0.f,0.f,0.f,0.f}, o11 = {0.f,0.f,0.f,0.f};
    f32x4 la0 = {0.f,0.f,0.f,0.f}, la1 = {0.f,0.f,0.f,0.f};   // l accumulators (row 0 used)
    float mr0 = 0.f, mr1 = 0.f;   // safe init: rows with all-negative logits flush harmlessly

    const char* gseg[3];
    int loseg[3];
    #pragma unroll
    for (int j = 0; j < 3; j++) {
        const int s = w * 3 + j;
        int loff;
        if (s < 8) loff = (lane >> 2) * 64  + (((lane & 3) ^ ((lane >> 3) & 3)) << 4);
        else       loff = (lane >> 3) * 128 + (((lane & 7) ^ ((lane >> 3) & 7)) << 4);
        gseg[j] = blob + s * 1024 + loff;
        loseg[j] = s * 512;
    }

    auto issue = [&](int t, int b) {
        #pragma unroll
        for (int j = 0; j < 3; j++)
            glds16(gseg[j] + (size_t)t * 12288, &B[b][loseg[j]]);
    };

    const int sw = (col >> 1) & 3;
    const short4v ones = {(short)0x3F80, (short)0x3F80, (short)0x3F80, (short)0x3F80};

    auto body = [&](int b) {
        const unsigned short* Bp = &B[b][0];
        short8 kh[4], kl[4];
        #pragma unroll
        for (int kc = 0; kc < 4; kc++) {
            const int ro = (col + kc * 16) * 32 + (quad ^ sw) * 8;
            kh[kc] = *(const short8*)&Bp[ro];
            kl[kc] = *(const short8*)&Bp[2048 + ro];
        }
        short4v va[4][2];
        #pragma unroll
        for (int kc = 0; kc < 4; kc++) {
            const int cl = kc * 2 + (quad >> 1);
            const int co = ((cl ^ (col & 7)) << 3) + (quad & 1) * 4;
            va[kc][0] = *(const short4v*)&Bp[4096 + (col     ) * 64 + co];
            va[kc][1] = *(const short4v*)&Bp[4096 + (col + 16) * 64 + co];
        }
        #pragma unroll
        for (int f = 0; f < 2; f++) {
            f32x4 s[4];
            #pragma unroll
            for (int kc = 0; kc < 4; kc++) {
                f32x4 a = {0.f, 0.f, 0.f, 0.f};
                a = __builtin_amdgcn_mfma_f32_16x16x32_bf16(kh[kc], ql[f], a, 0, 0, 0);
                a = __builtin_amdgcn_mfma_f32_16x16x32_bf16(kl[kc], qh[f], a, 0, 0, 0);
                a = __builtin_amdgcn_mfma_f32_16x16x32_bf16(kh[kc], qh[f], a, 0, 0, 0);
                s[kc] = a;
            }
            float mx = s[0][0];
            #pragma unroll
            for (int kc = 0; kc < 4; kc++)
                #pragma unroll
                for (int r = 0; r < 4; r++) mx = fmaxf(mx, s[kc][r]);
            mx = fmaxf(mx, __shfl_xor(mx, 16));
            mx = fmaxf(mx, __shfl_xor(mx, 32));

            float& mrf = f ? mr1 : mr0;
            f32x4& a0 = f ? o10 : o00;
            f32x4& a1 = f ? o11 : o01;
            f32x4& la = f ? la1 : la0;
            const float mnew = fmaxf(mrf, mx);
            if (__any(mx > mrf)) {   // lazy rescale: skip when no row's max moved
                const float alpha = __builtin_amdgcn_exp2f(mrf - mnew);
                #pragma unroll
                for (int r = 0; r < 4; r++) { a0[r] *= alpha; a1[r] *= alpha; }
                la[0] *= alpha;
            }
            mrf = mnew;

            short4v pb[4];
            #pragma unroll
            for (int kc = 0; kc < 4; kc++) {
                const float p0 = __builtin_amdgcn_exp2f(s[kc][0] - mnew);
                const float p1 = __builtin_amdgcn_exp2f(s[kc][1] - mnew);
                const float p2 = __builtin_amdgcn_exp2f(s[kc][2] - mnew);
                const float p3 = __builtin_amdgcn_exp2f(s[kc][3] - mnew);
                union { short4v v; unsigned u[2]; } P;
                P.u[0] = pack_bf16_rtz(p1, p0);   // P in [0,1]: truncation safe
                P.u[1] = pack_bf16_rtz(p3, p2);
                pb[kc] = P.v;
            }
            #pragma unroll
            for (int kc = 0; kc < 4; kc++) {
                a0 = __builtin_amdgcn_mfma_f32_16x16x16bf16_1k(va[kc][0], pb[kc], a0, 0, 0, 0);
                a1 = __builtin_amdgcn_mfma_f32_16x16x16bf16_1k(va[kc][1], pb[kc], a1, 0, 0, 0);
                la = __builtin_amdgcn_mfma_f32_16x16x16bf16_1k(ones,      pb[kc], la, 0, 0, 0);
            }
        }
    };

    issue(0, 0);
    __syncthreads();
    for (int t2 = 0; t2 < 16; t2++) {
        issue(2 * t2 + 1, 1);
        body(0);
        __syncthreads();
        if (t2 < 15) issue(2 * t2 + 2, 0);
        body(1);
        __syncthreads();
    }

    // epilogue: l = la[0] (cross-quad sum already done by the l-MFMA)
    const int n = nh >> 3, h = nh & 7;
    #pragma unroll
    for (int f = 0; f < 2; f++) {
        const float inv = 1.f / (f ? la1[0] : la0[0]);
        const f32x4& a0 = f ? o10 : o00;
        const f32x4& a1 = f ? o11 : o01;
        const int qrow = q0 + f * 64 + w * 16 + col;
        const size_t a = ((size_t)n * WH + qrow) * DM + h * DH + quad * 4;
        float4 x0 = *(const float4*)&X[a];
        float4 y0;
        y0.x = a0[0] * inv + x0.x;
        y0.y = a0[1] * inv + x0.y;
        y0.z = a0[2] * inv + x0.z;
        y0.w = a0[3] * inv + x0.w;
        *(float4*)&Out[a] = y0;
        float4 x1 = *(const float4*)&X[a + 16];
        float4 y1;
        y1.x = a1[0] * inv + x1.x;
        y1.y = a1[1] * inv + x1.y;
        y1.z = a1[2] * inv + x1.z;
        y1.w = a1[3] * inv + x1.w;
        *(float4*)&Out[a + 16] = y1;
    }
}

extern "C" void kernel_launch(void* const* d_in, const int* in_sizes, int n_in,
                              void* d_out, int out_size, void* d_ws, size_t ws_size,
                              hipStream_t stream) {
    const float* x  = (const float*)d_in[0];
    const float* Wq = (const float*)d_in[1];
    const float* bq = (const float*)d_in[2];
    const float* Wk = (const float*)d_in[3];
    const float* bk = (const float*)d_in[4];
    const float* Wv = (const float*)d_in[5];
    const float* bv = (const float*)d_in[6];
    float* out = (float*)d_out;

    const size_t elems = (size_t)NB * WH * DM;   // 4,194,304
    unsigned short* Qhi  = (unsigned short*)d_ws;
    unsigned short* Qlo  = Qhi + elems;
    unsigned short* KV   = Qlo + elems;                    // 64 heads x 32 tiles x 6144
    unsigned short* WThi = KV  + (size_t)64 * 32 * 6144;
    unsigned short* WTlo = WThi + (size_t)3 * DM * DM;

    // X hi/lo slabs live in d_out (16.78 MB); attn fully overwrites d_out after.
    unsigned short* Xhi = (unsigned short*)d_out;
    unsigned short* Xlo = Xhi + elems;

    prep<<<2096, 256, 0, stream>>>(x, Wq, Wk, Wv, Xhi, Xlo, WThi, WTlo);

    dim3 gg(128, 2, 3);
    qkv_mfma<<<gg, 256, 0, stream>>>(Xhi, Xlo, WThi, WTlo, bq, bk, bv,
                                     Qhi, Qlo, KV);

    dim3 ga(WH / 128, NB * NHD);   // (16, 64) = 1024 blocks
    attn<<<ga, 256, 0, stream>>>(Qhi, Qlo, KV, x, out);
}